// Round 2
// baseline (429.513 us; speedup 1.0000x reference)
//
#include <hip/hip_runtime.h>
#include <math.h>

#ifndef M_PI
#define M_PI 3.14159265358979323846
#endif

#define NPHI 511
#define NC   64
#define NT   256
#define NM   255

__device__ inline void fma4(float4& a, float s, const float4& b) {
    a.x = fmaf(s, b.x, a.x); a.y = fmaf(s, b.y, a.y);
    a.z = fmaf(s, b.z, a.z); a.w = fmaf(s, b.w, a.w);
}

#define FMA4R(ACC, A, B) \
    fma4(ACC[0], A.x, B); fma4(ACC[1], A.y, B); fma4(ACC[2], A.z, B); fma4(ACC[3], A.w, B);
#define FMA8(ACC, A0, A1, B) \
    fma4(ACC[0], A0.x, B); fma4(ACC[1], A0.y, B); fma4(ACC[2], A0.z, B); fma4(ACC[3], A0.w, B); \
    fma4(ACC[4], A1.x, B); fma4(ACC[5], A1.y, B); fma4(ACC[6], A1.z, B); fma4(ACC[7], A1.w, B);

// ---------------- K0: Gauss-Legendre nodes/weights (n=256), descending x ----
__global__ void k_gl_nodes(double* x64, double* w64) {
    int i = threadIdx.x;              // 0..255
    const int n = 256;
    double x = cos(M_PI * (i + 0.75) / (n + 0.5));
    for (int it = 0; it < 8; ++it) {
        double p0 = 1.0, p1 = x;
        for (int k = 2; k <= n; ++k) {
            double pk = ((2.0 * k - 1.0) * x * p1 - (k - 1.0) * p0) / (double)k;
            p0 = p1; p1 = pk;
        }
        double pd = n * (x * p1 - p0) / (x * x - 1.0);
        x -= p1 / pd;
    }
    double p0 = 1.0, p1 = x;
    for (int k = 2; k <= n; ++k) {
        double pk = ((2.0 * k - 1.0) * x * p1 - (k - 1.0) * p0) / (double)k;
        p0 = p1; p1 = pk;
    }
    double pd = n * (x * p1 - p0) / (x * x - 1.0);
    x64[i] = x;
    w64[i] = 2.0 / ((1.0 - x * x) * pd * pd);
}

// ---------------- K1: normalized assoc. Legendre table leg[m][l][t] --------
// m,l in [0,128), t in [0,256). leg=0 for l<m.
__global__ void k_legendre(const double* __restrict__ x64, float* __restrict__ leg) {
    int m = blockIdx.x;       // 0..127
    int t = threadIdx.x;      // 0..255
    double x = x64[t];
    double sx = sqrt(fmax(0.0, 1.0 - x * x));
    double pmm = 0.28209479177387814;   // 1/sqrt(4*pi)
    for (int k = 1; k <= m; ++k)
        pmm *= -sqrt((2.0 * k + 1.0) / (2.0 * k)) * sx;
    float* Lm = leg + (size_t)m * 128 * 256;
    for (int l = 0; l < m; ++l) Lm[l * 256 + t] = 0.f;
    Lm[m * 256 + t] = (float)pmm;
    if (m + 1 < 128) {
        double pl0 = pmm;
        double pl1 = sqrt(2.0 * m + 3.0) * x * pmm;
        Lm[(m + 1) * 256 + t] = (float)pl1;
        for (int l = m + 2; l < 128; ++l) {
            double dl = (double)l, dm = (double)m;
            double a = sqrt((4.0 * dl * dl - 1.0) / (dl * dl - dm * dm));
            double b = sqrt(((dl - 1.0) * (dl - 1.0) - dm * dm) / (4.0 * (dl - 1.0) * (dl - 1.0) - 1.0));
            double pl = a * (x * pl1 - b * pl0);
            pl0 = pl1; pl1 = pl;
            Lm[l * 256 + t] = (float)pl;
        }
    }
}

// ---------------- K2: DFT tables --------------------------------------------
// cFt[m][p] = cos(2pi p m/511)*scale, sFt[m][p] = -sin(...)*scale, m in [0,128), p padded to 512
// A5[p][k]: k=2m'+u, m=m'-127: u=0 -> cos(2pi p m/511), u=1 -> -sin(...). p padded to 512, k 510/511 zero.
__global__ void k_tables(float* __restrict__ cFt, float* __restrict__ sFt, float* __restrict__ A5) {
    int tid = blockIdx.x * blockDim.x + threadIdx.x;
    const double scale = 2.0 * M_PI / 511.0;
    if (tid < 128 * 512) {
        int m = tid >> 9, p = tid & 511;
        if (p < 511) {
            int r = (p * m) % 511;
            double ang = 2.0 * M_PI * (double)r / 511.0;
            cFt[tid] = (float)(cos(ang) * scale);
            sFt[tid] = (float)(-sin(ang) * scale);
        } else { cFt[tid] = 0.f; sFt[tid] = 0.f; }
    }
    if (tid < 512 * 512) {
        int p = tid >> 9, k = tid & 511;
        float v = 0.f;
        if (p < 511 && k < 510) {
            int mp = k >> 1, mm = mp - 127;
            int r = (int)(((long long)p * (long long)mm) % 511); if (r < 0) r += 511;
            double ang = 2.0 * M_PI * (double)r / 511.0;
            v = (k & 1) ? (float)(-sin(ang)) : (float)(cos(ang));
        }
        A5[tid] = v;
    }
}

// ---------------- K_phi: phi(l) = A_real . t_emb + i A_imag . t_emb --------
__global__ void k_phi(const float* __restrict__ Ar, const float* __restrict__ Ai,
                      const float* __restrict__ te, float* __restrict__ phi) {
    int l = threadIdx.x;  // 0..127
    float sr = 0.f, si = 0.f;
    for (int c = 0; c < 256; ++c) {
        float t = te[c];
        sr = fmaf(Ar[l * 256 + c], t, sr);
        si = fmaf(Ai[l * 256 + c], t, si);
    }
    phi[2 * l] = sr; phi[2 * l + 1] = si;
}

// ---------------- K3: stage 1, phi-DFT forward ------------------------------
// Fwr[m][t][c] = w[t]*sum_p cFt[m][p]*f[t][p][c]; Fwi likewise with sFt.
// Block per t (256), 512 threads, C-tile 128(m) x 64(c).
__global__ __launch_bounds__(512) void k_stage1(
        const float* __restrict__ f, const float* __restrict__ cFt,
        const float* __restrict__ sFt, const double* __restrict__ w64,
        float* __restrict__ Fwr, float* __restrict__ Fwi) {
    __shared__ __align__(16) float Ac[16][128];
    __shared__ __align__(16) float Sc[16][128];
    __shared__ __align__(16) float Bs[16][64];
    int t = blockIdx.x;
    int tid = threadIdx.x;
    int tx4 = (tid & 15) * 4;
    int ty  = tid >> 4;            // 0..31
    int ty4 = ty * 4;              // row base 0..124
    float4 accR[4], accI[4];
    #pragma unroll
    for (int j = 0; j < 4; ++j) { accR[j] = make_float4(0,0,0,0); accI[j] = make_float4(0,0,0,0); }
    const float* fb = f + (size_t)t * (NPHI * NC);
    int u = tid & 3, mrow = tid >> 2;          // mrow 0..127
    int bkk = tid >> 4, bc4 = (tid & 15) * 4;  // for tid<256
    #pragma unroll 1
    for (int p0 = 0; p0 < 512; p0 += 16) {
        float4 ca = *(const float4*)(cFt + mrow * 512 + p0 + u * 4);
        float4 sa = *(const float4*)(sFt + mrow * 512 + p0 + u * 4);
        float4 bv = make_float4(0,0,0,0);
        if (tid < 256) {
            int p = p0 + bkk;
            if (p < NPHI) bv = *(const float4*)(fb + p * NC + bc4);
        }
        __syncthreads();
        Ac[u*4+0][mrow] = ca.x; Ac[u*4+1][mrow] = ca.y; Ac[u*4+2][mrow] = ca.z; Ac[u*4+3][mrow] = ca.w;
        Sc[u*4+0][mrow] = sa.x; Sc[u*4+1][mrow] = sa.y; Sc[u*4+2][mrow] = sa.z; Sc[u*4+3][mrow] = sa.w;
        if (tid < 256) *(float4*)&Bs[bkk][bc4] = bv;
        __syncthreads();
        #pragma unroll
        for (int kk = 0; kk < 16; ++kk) {
            float4 b  = *(float4*)&Bs[kk][tx4];
            float4 a  = *(float4*)&Ac[kk][ty4];
            float4 s  = *(float4*)&Sc[kk][ty4];
            FMA4R(accR, a, b);
            FMA4R(accI, s, b);
        }
    }
    float wf = (float)w64[t];
    size_t cbase = (size_t)t * 64 + tx4;
    #pragma unroll
    for (int j = 0; j < 4; ++j) {
        int m = ty4 + j;
        float4 r = accR[j]; r.x *= wf; r.y *= wf; r.z *= wf; r.w *= wf;
        float4 s = accI[j]; s.x *= wf; s.y *= wf; s.z *= wf; s.w *= wf;
        *(float4*)(Fwr + (size_t)m * 16384 + cbase) = r;
        *(float4*)(Fwi + (size_t)m * 16384 + cbase) = s;
    }
}

// ---------------- K4: stage 2, forward Legendre (batched over m) ------------
// Xr[m][l][c] = sum_t leg[m][l][t]*Fwr[m][t][c]; Xi likewise.
// Grid (m=128, lh=2), 256 threads, C-tile 64(l) x 64(c).
__global__ __launch_bounds__(256) void k_stage2(
        const float* __restrict__ leg, const float* __restrict__ Fwr,
        const float* __restrict__ Fwi, float* __restrict__ Xr, float* __restrict__ Xi) {
    __shared__ __align__(16) float As[16][64];
    __shared__ __align__(16) float Br[16][64];
    __shared__ __align__(16) float Bi[16][64];
    int m = blockIdx.x, lh = blockIdx.y;
    int tid = threadIdx.x;
    int tx4 = (tid & 15) * 4, ty4 = (tid >> 4) * 4;
    float4 accR[4], accI[4];
    #pragma unroll
    for (int j = 0; j < 4; ++j) { accR[j] = make_float4(0,0,0,0); accI[j] = make_float4(0,0,0,0); }
    const float* lm = leg + (size_t)m * 32768 + (size_t)lh * 64 * 256;
    const float* br = Fwr + (size_t)m * 16384;
    const float* bi = Fwi + (size_t)m * 16384;
    int u = tid & 3, lrow = tid >> 2;          // 0..63
    int bkk = tid >> 4, bc4 = (tid & 15) * 4;
    #pragma unroll 1
    for (int t0 = 0; t0 < 256; t0 += 16) {
        float4 av  = *(const float4*)(lm + lrow * 256 + t0 + u * 4);
        float4 brv = *(const float4*)(br + (t0 + bkk) * 64 + bc4);
        float4 biv = *(const float4*)(bi + (t0 + bkk) * 64 + bc4);
        __syncthreads();
        As[u*4+0][lrow] = av.x; As[u*4+1][lrow] = av.y; As[u*4+2][lrow] = av.z; As[u*4+3][lrow] = av.w;
        *(float4*)&Br[bkk][bc4] = brv;
        *(float4*)&Bi[bkk][bc4] = biv;
        __syncthreads();
        #pragma unroll
        for (int kk = 0; kk < 16; ++kk) {
            float4 a  = *(float4*)&As[kk][ty4];
            float4 vr = *(float4*)&Br[kk][tx4];
            float4 vi = *(float4*)&Bi[kk][tx4];
            FMA4R(accR, a, vr);
            FMA4R(accI, a, vi);
        }
    }
    #pragma unroll
    for (int j = 0; j < 4; ++j) {
        int l = lh * 64 + ty4 + j;
        *(float4*)(Xr + (size_t)m * 8192 + l * 64 + tx4) = accR[j];
        *(float4*)(Xi + (size_t)m * 8192 + l * 64 + tx4) = accI[j];
    }
}

// ---------------- K5: stage 3, channel mix * phi, with +-m reconstruction ---
// Or'[m'][l][co], Oi'[m'][l][co]  (sigma(m) folded in for stage 4)
__global__ __launch_bounds__(256) void k_stage3(
        const float* __restrict__ Xr, const float* __restrict__ Xi,
        const float* __restrict__ Rr, const float* __restrict__ Ri,
        const float* __restrict__ phi, float* __restrict__ Or, float* __restrict__ Oi) {
    __shared__ float RsR[64][64];   // [ci][co]
    __shared__ float RsI[64][64];
    __shared__ float XsR[4][64];
    __shared__ float XsI[4][64];
    int l = blockIdx.x, mh = blockIdx.y;
    int tid = threadIdx.x;
    for (int idx = tid; idx < 4096; idx += 256) {
        int co = idx >> 6, ci = idx & 63;
        RsR[ci][co] = Rr[(size_t)l * 4096 + idx];
        RsI[ci][co] = Ri[(size_t)l * 4096 + idx];
    }
    float phr = phi[2 * l], phii = phi[2 * l + 1];
    int co = tid & 63, mg = tid >> 6;
    int m0base = mh * 128;
    #pragma unroll 1
    for (int it = 0; it < 32; ++it) {
        int mp = m0base + it * 4 + mg;
        __syncthreads();
        {
            int ci = tid & 63;
            float xr = 0.f, xi = 0.f;
            if (mp < NM) {
                int mm = mp - 127;
                int am = mm < 0 ? -mm : mm;
                size_t idx = (size_t)am * 8192 + (size_t)l * 64 + ci;
                float vr = Xr[idx], vi = Xi[idx];
                if (mm >= 0) { xr = vr; xi = vi; }
                else { float s = (am & 1) ? -1.f : 1.f; xr = s * vr; xi = -s * vi; }
            }
            XsR[mg][ci] = xr; XsI[mg][ci] = xi;
        }
        __syncthreads();
        if (mp < NM) {
            float ar0=0,ar1=0,ar2=0,ar3=0, ai0=0,ai1=0,ai2=0,ai3=0;
            #pragma unroll
            for (int ci = 0; ci < 64; ci += 4) {
                float x0r=XsR[mg][ci+0], x0i=XsI[mg][ci+0];
                float x1r=XsR[mg][ci+1], x1i=XsI[mg][ci+1];
                float x2r=XsR[mg][ci+2], x2i=XsI[mg][ci+2];
                float x3r=XsR[mg][ci+3], x3i=XsI[mg][ci+3];
                float r0=RsR[ci+0][co], q0=RsI[ci+0][co];
                float r1=RsR[ci+1][co], q1=RsI[ci+1][co];
                float r2=RsR[ci+2][co], q2=RsI[ci+2][co];
                float r3=RsR[ci+3][co], q3=RsI[ci+3][co];
                ar0 = fmaf(r0,x0r,fmaf(-q0,x0i,ar0)); ai0 = fmaf(r0,x0i,fmaf(q0,x0r,ai0));
                ar1 = fmaf(r1,x1r,fmaf(-q1,x1i,ar1)); ai1 = fmaf(r1,x1i,fmaf(q1,x1r,ai1));
                ar2 = fmaf(r2,x2r,fmaf(-q2,x2i,ar2)); ai2 = fmaf(r2,x2i,fmaf(q2,x2r,ai2));
                ar3 = fmaf(r3,x3r,fmaf(-q3,x3i,ar3)); ai3 = fmaf(r3,x3i,fmaf(q3,x3r,ai3));
            }
            float ar = (ar0 + ar1) + (ar2 + ar3);
            float ai = (ai0 + ai1) + (ai2 + ai3);
            int mm = mp - 127; int am = mm < 0 ? -mm : mm;
            float sg = (mm < 0 && (am & 1)) ? -1.f : 1.f;
            float outr = sg * (phr * ar - phii * ai);
            float outi = sg * (phr * ai + phii * ar);
            Or[(size_t)mp * 8192 + (size_t)l * 64 + co] = outr;
            Oi[(size_t)mp * 8192 + (size_t)l * 64 + co] = outi;
        }
    }
}

// ---------------- K6: stage 4, inverse Legendre (batched over m') -----------
// G[2m'][t][c] = sum_l leg[|m|][l][t]*Or'[m'][l][c]; G[2m'+1] from Oi'.
// Grid (m'=255, th=2), 256 threads, C-tile 128(t) x 64(c).
__global__ __launch_bounds__(256) void k_stage4(
        const float* __restrict__ leg, const float* __restrict__ Or,
        const float* __restrict__ Oi, float* __restrict__ G) {
    __shared__ __align__(16) float As[16][128];
    __shared__ __align__(16) float Br[16][64];
    __shared__ __align__(16) float Bi[16][64];
    int mp = blockIdx.x, th = blockIdx.y;
    int mm = mp - 127; int am = mm < 0 ? -mm : mm;
    int tid = threadIdx.x;
    int tx4 = (tid & 15) * 4, ty4 = (tid >> 4) * 4;
    float4 accR[8], accI[8];
    #pragma unroll
    for (int j = 0; j < 8; ++j) { accR[j] = make_float4(0,0,0,0); accI[j] = make_float4(0,0,0,0); }
    const float* lm = leg + (size_t)am * 32768;
    const float* br = Or + (size_t)mp * 8192;
    const float* bi = Oi + (size_t)mp * 8192;
    int akk = tid >> 4, atq4 = (tid & 15) * 4;
    int tbase = th * 128;
    int k0s = am & ~15;
    #pragma unroll 1
    for (int k0 = k0s; k0 < 128; k0 += 16) {
        float4 a0  = *(const float4*)(lm + (k0 + akk) * 256 + tbase + atq4);
        float4 a1  = *(const float4*)(lm + (k0 + akk) * 256 + tbase + 64 + atq4);
        float4 brv = *(const float4*)(br + (k0 + akk) * 64 + atq4);
        float4 biv = *(const float4*)(bi + (k0 + akk) * 64 + atq4);
        __syncthreads();
        *(float4*)&As[akk][atq4] = a0;
        *(float4*)&As[akk][64 + atq4] = a1;
        *(float4*)&Br[akk][atq4] = brv;
        *(float4*)&Bi[akk][atq4] = biv;
        __syncthreads();
        #pragma unroll
        for (int kk = 0; kk < 16; ++kk) {
            float4 ar0 = *(float4*)&As[kk][ty4];
            float4 ar1 = *(float4*)&As[kk][64 + ty4];
            float4 vr  = *(float4*)&Br[kk][tx4];
            float4 vi  = *(float4*)&Bi[kk][tx4];
            FMA8(accR, ar0, ar1, vr);
            FMA8(accI, ar0, ar1, vi);
        }
    }
    float* gr = G + (size_t)(2 * mp) * 16384;
    float* gi = G + (size_t)(2 * mp + 1) * 16384;
    #pragma unroll
    for (int j = 0; j < 4; ++j) {
        int r0 = tbase + ty4 + j, r1 = tbase + 64 + ty4 + j;
        *(float4*)(gr + r0 * 64 + tx4) = accR[j];
        *(float4*)(gr + r1 * 64 + tx4) = accR[4 + j];
        *(float4*)(gi + r0 * 64 + tx4) = accI[j];
        *(float4*)(gi + r1 * 64 + tx4) = accI[4 + j];
    }
}

// ---------------- K7: stage 5, inverse phi-DFT ------------------------------
// out[t][p][c] = sum_k A5[p][k]*G[k][t][c], K=512 (zero-padded).
// Grid (t=256, pb=4), 256 threads, C-tile 128(p) x 64(c).
__global__ __launch_bounds__(256) void k_stage5(
        const float* __restrict__ A5, const float* __restrict__ G, float* __restrict__ out) {
    __shared__ __align__(16) float As[16][128];
    __shared__ __align__(16) float Bs[16][64];
    int t = blockIdx.x, pb = blockIdx.y;
    int tid = threadIdx.x;
    int tx4 = (tid & 15) * 4, ty4 = (tid >> 4) * 4;
    float4 acc[8];
    #pragma unroll
    for (int j = 0; j < 8; ++j) acc[j] = make_float4(0,0,0,0);
    int u = tid & 3, prow = tid >> 2;          // 0..63
    int bkk = tid >> 4, bc4 = (tid & 15) * 4;
    int pbase = pb * 128;
    #pragma unroll 1
    for (int k0 = 0; k0 < 512; k0 += 16) {
        float4 a0 = *(const float4*)(A5 + (size_t)(pbase + prow) * 512 + k0 + u * 4);
        float4 a1 = *(const float4*)(A5 + (size_t)(pbase + prow + 64) * 512 + k0 + u * 4);
        float4 bv = *(const float4*)(G + (size_t)(k0 + bkk) * 16384 + t * 64 + bc4);
        __syncthreads();
        As[u*4+0][prow] = a0.x; As[u*4+1][prow] = a0.y; As[u*4+2][prow] = a0.z; As[u*4+3][prow] = a0.w;
        As[u*4+0][prow+64] = a1.x; As[u*4+1][prow+64] = a1.y; As[u*4+2][prow+64] = a1.z; As[u*4+3][prow+64] = a1.w;
        *(float4*)&Bs[bkk][bc4] = bv;
        __syncthreads();
        #pragma unroll
        for (int kk = 0; kk < 16; ++kk) {
            float4 b   = *(float4*)&Bs[kk][tx4];
            float4 a0v = *(float4*)&As[kk][ty4];
            float4 a1v = *(float4*)&As[kk][64 + ty4];
            FMA8(acc, a0v, a1v, b);
        }
    }
    #pragma unroll
    for (int j = 0; j < 4; ++j) {
        int p0 = pbase + ty4 + j, p1 = pbase + 64 + ty4 + j;
        if (p0 < NPHI) *(float4*)(out + (size_t)t * 32704 + p0 * 64 + tx4) = acc[j];
        if (p1 < NPHI) *(float4*)(out + (size_t)t * 32704 + p1 * 64 + tx4) = acc[4 + j];
    }
}

extern "C" void kernel_launch(void* const* d_in, const int* in_sizes, int n_in,
                              void* d_out, int out_size, void* d_ws, size_t ws_size,
                              hipStream_t stream) {
    const float* x    = (const float*)d_in[0];
    const float* temb = (const float*)d_in[1];
    const float* Ar   = (const float*)d_in[2];
    const float* Ai   = (const float*)d_in[3];
    const float* Rr   = (const float*)d_in[4];
    const float* Ri   = (const float*)d_in[5];
    float* out = (float*)d_out;

    char* ws = (char*)d_ws;
    size_t off = 0;
    auto alloc = [&](size_t bytes) -> void* {
        void* p = ws + off;
        off = (off + bytes + 255) & ~(size_t)255;
        return p;
    };
    double* x64 = (double*)alloc(256 * 8);
    double* w64 = (double*)alloc(256 * 8);
    float*  phi = (float*)alloc(256 * 4);
    float*  leg = (float*)alloc((size_t)128 * 128 * 256 * 4);   // 16.78 MB
    float*  cFt = (float*)alloc((size_t)128 * 512 * 4);
    float*  sFt = (float*)alloc((size_t)128 * 512 * 4);
    float*  A5  = (float*)alloc((size_t)512 * 512 * 4);
    float*  Fwr = (float*)alloc((size_t)128 * 256 * 64 * 4);    // 8.39 MB (reused as Or)
    float*  Fwi = (float*)alloc((size_t)128 * 256 * 64 * 4);    // reused as Oi
    float*  Xr  = (float*)alloc((size_t)128 * 128 * 64 * 4);
    float*  Xi  = (float*)alloc((size_t)128 * 128 * 64 * 4);
    float*  G   = (float*)alloc((size_t)512 * 256 * 64 * 4);    // 33.55 MB
    if (off > ws_size) return;   // workspace too small: visible as validation failure
    float* Or = Fwr;  // Fw dead after stage 2
    float* Oi = Fwi;

    hipLaunchKernelGGL(k_gl_nodes, dim3(1),            dim3(256), 0, stream, x64, w64);
    hipLaunchKernelGGL(k_legendre, dim3(128),          dim3(256), 0, stream, x64, leg);
    hipLaunchKernelGGL(k_tables,   dim3(1024),         dim3(256), 0, stream, cFt, sFt, A5);
    hipLaunchKernelGGL(k_phi,      dim3(1),            dim3(128), 0, stream, Ar, Ai, temb, phi);
    hipLaunchKernelGGL(k_stage1,   dim3(256),          dim3(512), 0, stream, x, cFt, sFt, w64, Fwr, Fwi);
    hipLaunchKernelGGL(k_stage2,   dim3(128, 2),       dim3(256), 0, stream, leg, Fwr, Fwi, Xr, Xi);
    hipLaunchKernelGGL(k_stage3,   dim3(128, 2),       dim3(256), 0, stream, Xr, Xi, Rr, Ri, phi, Or, Oi);
    hipLaunchKernelGGL(k_stage4,   dim3(255, 2),       dim3(256), 0, stream, leg, Or, Oi, G);
    hipLaunchKernelGGL(k_stage5,   dim3(256, 4),       dim3(256), 0, stream, A5, G, out);
}

// Round 3
// 214.763 us; speedup vs baseline: 1.9999x; 1.9999x over previous
//
#include <hip/hip_runtime.h>
#include <math.h>

#ifndef M_PI
#define M_PI 3.14159265358979323846
#endif

typedef _Float16 f16;
typedef _Float16 f16x8 __attribute__((ext_vector_type(8)));
typedef float f32x4 __attribute__((ext_vector_type(4)));

#define NPHI 511
#define NM   255

// ---------------- K0: Gauss-Legendre nodes/weights (n=256), descending x ----
__global__ void k_gl_nodes(double* x64, double* w64) {
    __shared__ double c1[257], c2[257];
    int i = threadIdx.x;              // 0..255
    for (int k = i; k <= 256; k += 256) {
        if (k >= 2) { c1[k] = (2.0 * k - 1.0) / k; c2[k] = (k - 1.0) / k; }
    }
    __syncthreads();
    const int n = 256;
    double x = cos(M_PI * (i + 0.75) / (n + 0.5));
    double p1 = 0.0, pd = 1.0;
    for (int it = 0; it < 5; ++it) {
        double p0 = 1.0; p1 = x;
        for (int k = 2; k <= n; ++k) {
            double pk = c1[k] * x * p1 - c2[k] * p0;
            p0 = p1; p1 = pk;
        }
        pd = n * (x * p1 - p0) / (x * x - 1.0);
        x -= p1 / pd;     // final iter: delta ~1e-15, stale pd error negligible
    }
    x64[i] = x;
    w64[i] = 2.0 / ((1.0 - x * x) * pd * pd);
}

// ---------------- K1: assoc. Legendre table legh[m][l][t] fp16 --------------
__global__ void k_leg_h(const double* __restrict__ x64, f16* __restrict__ legh) {
    __shared__ double sa[128], sb[128], sf[128];
    int m = blockIdx.x, t = threadIdx.x;
    if (t < 128) {
        double dl = t, dm = m;
        if (t >= 2) {
            sa[t] = sqrt((4.0 * dl * dl - 1.0) / (dl * dl - dm * dm));
            sb[t] = sqrt(((dl - 1.0) * (dl - 1.0) - dm * dm) / (4.0 * (dl - 1.0) * (dl - 1.0) - 1.0));
        }
        if (t >= 1) sf[t] = -sqrt((2.0 * t + 1.0) / (2.0 * t));
    }
    __syncthreads();
    double x = x64[t];
    double sx = sqrt(fmax(0.0, 1.0 - x * x));
    double pmm = 0.28209479177387814;   // 1/sqrt(4*pi)
    for (int k = 1; k <= m; ++k) pmm *= sf[k] * sx;
    f16* Lm = legh + (size_t)m * (128 * 256);
    for (int l = 0; l < m; ++l) Lm[l * 256 + t] = (f16)0.f;
    Lm[m * 256 + t] = (f16)pmm;
    if (m + 1 < 128) {
        double pl0 = pmm;
        double pl1 = sqrt(2.0 * m + 3.0) * x * pmm;
        Lm[(m + 1) * 256 + t] = (f16)pl1;
        for (int l = m + 2; l < 128; ++l) {
            double pl = sa[l] * (x * pl1 - sb[l] * pl0);
            pl0 = pl1; pl1 = pl;
            Lm[l * 256 + t] = (f16)pl;
        }
    }
}

// ---------------- K2: DFT tables (fp16) -------------------------------------
__global__ void k_tables_h(f16* __restrict__ cF, f16* __restrict__ sF, f16* __restrict__ A5) {
    int tid = blockIdx.x * blockDim.x + threadIdx.x;
    const double scale = 2.0 * M_PI / 511.0;
    if (tid < 128 * 512) {
        int m = tid >> 9, p = tid & 511;
        float cv = 0.f, sv = 0.f;
        if (p < 511) {
            int r = (p * m) % 511;
            double ang = 2.0 * M_PI * (double)r / 511.0;
            cv = (float)(cos(ang) * scale);
            sv = (float)(-sin(ang) * scale);
        }
        cF[tid] = (f16)cv; sF[tid] = (f16)sv;
    }
    {
        int p = tid >> 9, k = tid & 511;
        float v = 0.f;
        if (p < 511 && k < 510) {
            int mp = k >> 1, mm = mp - 127;
            int r = (int)(((long long)p * (long long)mm) % 511); if (r < 0) r += 511;
            double ang = 2.0 * M_PI * (double)r / 511.0;
            v = (k & 1) ? (float)(-sin(ang)) : (float)(cos(ang));
        }
        A5[tid] = (f16)v;
    }
}

// ---------------- K_phi ------------------------------------------------------
__global__ void k_phi(const float* __restrict__ Ar, const float* __restrict__ Ai,
                      const float* __restrict__ te, float* __restrict__ phi) {
    int l = threadIdx.x;  // 0..127
    float sr = 0.f, si = 0.f;
    for (int c = 0; c < 256; ++c) {
        float t = te[c];
        sr = fmaf(Ar[l * 256 + c], t, sr);
        si = fmaf(Ai[l * 256 + c], t, si);
    }
    phi[2 * l] = sr; phi[2 * l + 1] = si;
}

// ---------------- K_convert: x[t][p][c] f32 -> xh[t][c][p(512)] f16 ---------
__global__ __launch_bounds__(256) void k_convert(const float* __restrict__ x, f16* __restrict__ xh) {
    __shared__ float Ls[64][68];
    int t = blockIdx.x, pt = blockIdx.y, tid = threadIdx.x;
    int p0 = pt * 64;
    const float* xb = x + (size_t)t * (NPHI * 64);
    #pragma unroll
    for (int e = 0; e < 4; ++e) {
        int idx = tid + e * 256;
        int row = idx >> 4, c4 = (idx & 15) * 4;
        int p = p0 + row;
        float4 v = make_float4(0.f, 0.f, 0.f, 0.f);
        if (p < NPHI) v = *(const float4*)(xb + (size_t)p * 64 + c4);
        *(float4*)&Ls[row][c4] = v;
    }
    __syncthreads();
    #pragma unroll
    for (int e = 0; e < 2; ++e) {
        int idx = tid + e * 256;
        int c = idx >> 3, r8 = (idx & 7) * 8;
        __align__(16) f16 tmp[8];
        #pragma unroll
        for (int j = 0; j < 8; ++j) tmp[j] = (f16)Ls[r8 + j][c];
        *(float4*)(xh + (size_t)t * (64 * 512) + (size_t)c * 512 + p0 + r8) = *(float4*)tmp;
    }
}

// ---------------- generic fp16 transpose [b][R][C] -> [b][C][R] -------------
__global__ __launch_bounds__(256) void k_tr16(const f16* __restrict__ src, f16* __restrict__ dst,
                                              int R, int C) {
    __shared__ f16 Ts[64][72];
    int b = blockIdx.x, tile = blockIdx.y, tid = threadIdx.x;
    int ctiles = C >> 6;
    int rt = tile / ctiles, ct = tile - rt * ctiles;
    const f16* s = src + (size_t)b * R * C + (size_t)(rt * 64) * C + ct * 64;
    #pragma unroll
    for (int e = 0; e < 2; ++e) {
        int idx = tid + e * 256;
        int row = idx >> 3, c8 = (idx & 7) * 8;
        *(float4*)&Ts[row][c8] = *(const float4*)(s + (size_t)row * C + c8);
    }
    __syncthreads();
    f16* d = dst + (size_t)b * R * C + (size_t)(ct * 64) * R + rt * 64;
    #pragma unroll
    for (int e = 0; e < 2; ++e) {
        int idx = tid + e * 256;
        int c = idx >> 3, r8 = (idx & 7) * 8;
        __align__(16) f16 tmp[8];
        #pragma unroll
        for (int j = 0; j < 8; ++j) tmp[j] = Ts[r8 + j][c];
        *(float4*)(d + (size_t)c * R + r8) = *(float4*)tmp;
    }
}

// ---------------- K3: stage 1 MFMA: Fw[m][t][c] = w(t)*T[m][p]*f[p][c] ------
// grid (t=256, mt=2), 256 thr. A0=cos,A1=sin [64rows m][K=512]; B=xh[t][c][512].
__global__ __launch_bounds__(256) void k_g1(const f16* __restrict__ xh, const f16* __restrict__ cF,
        const f16* __restrict__ sF, const double* __restrict__ w64,
        f16* __restrict__ FwR, f16* __restrict__ FwI) {
    __shared__ f16 Ac[64][40], An[64][40], Bs[64][40];
    int t = blockIdx.x, mt = blockIdx.y, tid = threadIdx.x;
    const f16* A0 = cF + (size_t)(mt * 64) * 512;
    const f16* A1 = sF + (size_t)(mt * 64) * 512;
    const f16* B  = xh + (size_t)t * (64 * 512);
    f32x4 acc[2][2][2];  // [tab][mf][nf]
    #pragma unroll
    for (int a = 0; a < 2; ++a)
        #pragma unroll
        for (int b = 0; b < 2; ++b)
            #pragma unroll
            for (int c = 0; c < 2; ++c) acc[a][b][c] = (f32x4){0.f, 0.f, 0.f, 0.f};
    int lane = tid & 63, wid = tid >> 6;
    int wm = wid & 1, wn = wid >> 1;
    int fr = lane & 15, g8 = (lane >> 4) * 8;
    int row = tid >> 2, k8 = (tid & 3) * 8;
    for (int kt = 0; kt < 16; ++kt) {
        float4 va = *(const float4*)(A0 + (size_t)row * 512 + kt * 32 + k8);
        float4 vn = *(const float4*)(A1 + (size_t)row * 512 + kt * 32 + k8);
        float4 vb = *(const float4*)(B  + (size_t)row * 512 + kt * 32 + k8);
        __syncthreads();
        *(float4*)&Ac[row][k8] = va;
        *(float4*)&An[row][k8] = vn;
        *(float4*)&Bs[row][k8] = vb;
        __syncthreads();
        f16x8 b0 = *(f16x8*)&Bs[wn * 32 + fr][g8];
        f16x8 b1 = *(f16x8*)&Bs[wn * 32 + 16 + fr][g8];
        f16x8 a0 = *(f16x8*)&Ac[wm * 32 + fr][g8];
        f16x8 a1 = *(f16x8*)&Ac[wm * 32 + 16 + fr][g8];
        f16x8 s0 = *(f16x8*)&An[wm * 32 + fr][g8];
        f16x8 s1 = *(f16x8*)&An[wm * 32 + 16 + fr][g8];
        acc[0][0][0] = __builtin_amdgcn_mfma_f32_16x16x32_f16(a0, b0, acc[0][0][0], 0, 0, 0);
        acc[0][0][1] = __builtin_amdgcn_mfma_f32_16x16x32_f16(a0, b1, acc[0][0][1], 0, 0, 0);
        acc[0][1][0] = __builtin_amdgcn_mfma_f32_16x16x32_f16(a1, b0, acc[0][1][0], 0, 0, 0);
        acc[0][1][1] = __builtin_amdgcn_mfma_f32_16x16x32_f16(a1, b1, acc[0][1][1], 0, 0, 0);
        acc[1][0][0] = __builtin_amdgcn_mfma_f32_16x16x32_f16(s0, b0, acc[1][0][0], 0, 0, 0);
        acc[1][0][1] = __builtin_amdgcn_mfma_f32_16x16x32_f16(s0, b1, acc[1][0][1], 0, 0, 0);
        acc[1][1][0] = __builtin_amdgcn_mfma_f32_16x16x32_f16(s1, b0, acc[1][1][0], 0, 0, 0);
        acc[1][1][1] = __builtin_amdgcn_mfma_f32_16x16x32_f16(s1, b1, acc[1][1][1], 0, 0, 0);
    }
    float wf = (float)w64[t];
    int rg = (lane >> 4) * 4;
    #pragma unroll
    for (int mf = 0; mf < 2; ++mf)
        #pragma unroll
        for (int nf = 0; nf < 2; ++nf) {
            int c = wn * 32 + nf * 16 + fr;
            #pragma unroll
            for (int r = 0; r < 4; ++r) {
                int m = mt * 64 + wm * 32 + mf * 16 + rg + r;
                FwR[((size_t)m * 256 + t) * 64 + c] = (f16)(acc[0][mf][nf][r] * wf);
                FwI[((size_t)m * 256 + t) * 64 + c] = (f16)(acc[1][mf][nf][r] * wf);
            }
        }
}

// ---------------- K4: stage 2 MFMA: X[m][l][c] = leg[l][t]*Fw[t][c] ---------
// grid (m=128, lt=2). A=legh[m][lt*64..][t K=256]; B0/B1 = FwT[m][c][t].
__global__ __launch_bounds__(256) void k_g2(const f16* __restrict__ legh, const f16* __restrict__ BTr,
        const f16* __restrict__ BTi, float* __restrict__ Xr, float* __restrict__ Xi) {
    __shared__ f16 As[64][40], Br[64][40], Bi[64][40];
    int m = blockIdx.x, lt = blockIdx.y, tid = threadIdx.x;
    const f16* A  = legh + (size_t)m * (128 * 256) + (size_t)(lt * 64) * 256;
    const f16* B0 = BTr + (size_t)m * (64 * 256);
    const f16* B1 = BTi + (size_t)m * (64 * 256);
    f32x4 acc[2][2][2];  // [bsel][mf][nf]
    #pragma unroll
    for (int a = 0; a < 2; ++a)
        #pragma unroll
        for (int b = 0; b < 2; ++b)
            #pragma unroll
            for (int c = 0; c < 2; ++c) acc[a][b][c] = (f32x4){0.f, 0.f, 0.f, 0.f};
    int lane = tid & 63, wid = tid >> 6;
    int wm = wid & 1, wn = wid >> 1;
    int fr = lane & 15, g8 = (lane >> 4) * 8;
    int row = tid >> 2, k8 = (tid & 3) * 8;
    for (int kt = 0; kt < 8; ++kt) {
        float4 va = *(const float4*)(A  + (size_t)row * 256 + kt * 32 + k8);
        float4 vr = *(const float4*)(B0 + (size_t)row * 256 + kt * 32 + k8);
        float4 vi = *(const float4*)(B1 + (size_t)row * 256 + kt * 32 + k8);
        __syncthreads();
        *(float4*)&As[row][k8] = va;
        *(float4*)&Br[row][k8] = vr;
        *(float4*)&Bi[row][k8] = vi;
        __syncthreads();
        f16x8 a0 = *(f16x8*)&As[wm * 32 + fr][g8];
        f16x8 a1 = *(f16x8*)&As[wm * 32 + 16 + fr][g8];
        f16x8 r0 = *(f16x8*)&Br[wn * 32 + fr][g8];
        f16x8 r1 = *(f16x8*)&Br[wn * 32 + 16 + fr][g8];
        f16x8 i0 = *(f16x8*)&Bi[wn * 32 + fr][g8];
        f16x8 i1 = *(f16x8*)&Bi[wn * 32 + 16 + fr][g8];
        acc[0][0][0] = __builtin_amdgcn_mfma_f32_16x16x32_f16(a0, r0, acc[0][0][0], 0, 0, 0);
        acc[0][0][1] = __builtin_amdgcn_mfma_f32_16x16x32_f16(a0, r1, acc[0][0][1], 0, 0, 0);
        acc[0][1][0] = __builtin_amdgcn_mfma_f32_16x16x32_f16(a1, r0, acc[0][1][0], 0, 0, 0);
        acc[0][1][1] = __builtin_amdgcn_mfma_f32_16x16x32_f16(a1, r1, acc[0][1][1], 0, 0, 0);
        acc[1][0][0] = __builtin_amdgcn_mfma_f32_16x16x32_f16(a0, i0, acc[1][0][0], 0, 0, 0);
        acc[1][0][1] = __builtin_amdgcn_mfma_f32_16x16x32_f16(a0, i1, acc[1][0][1], 0, 0, 0);
        acc[1][1][0] = __builtin_amdgcn_mfma_f32_16x16x32_f16(a1, i0, acc[1][1][0], 0, 0, 0);
        acc[1][1][1] = __builtin_amdgcn_mfma_f32_16x16x32_f16(a1, i1, acc[1][1][1], 0, 0, 0);
    }
    int rg = (lane >> 4) * 4;
    #pragma unroll
    for (int mf = 0; mf < 2; ++mf)
        #pragma unroll
        for (int nf = 0; nf < 2; ++nf) {
            int c = wn * 32 + nf * 16 + fr;
            #pragma unroll
            for (int r = 0; r < 4; ++r) {
                int l = lt * 64 + wm * 32 + mf * 16 + rg + r;
                Xr[(size_t)m * 8192 + l * 64 + c] = acc[0][mf][nf][r];
                Xi[(size_t)m * 8192 + l * 64 + c] = acc[1][mf][nf][r];
            }
        }
}

// ---------------- K5: stage 3, channel mix * phi (fp32 VALU) ----------------
__global__ __launch_bounds__(256) void k_stage3(
        const float* __restrict__ Xr, const float* __restrict__ Xi,
        const float* __restrict__ Rr, const float* __restrict__ Ri,
        const float* __restrict__ phi, f16* __restrict__ Or, f16* __restrict__ Oi) {
    __shared__ float RsR[64][64];
    __shared__ float RsI[64][64];
    __shared__ float XsR[4][64];
    __shared__ float XsI[4][64];
    int l = blockIdx.x, mh = blockIdx.y;
    int tid = threadIdx.x;
    for (int idx = tid; idx < 4096; idx += 256) {
        int co = idx >> 6, ci = idx & 63;
        RsR[ci][co] = Rr[(size_t)l * 4096 + idx];
        RsI[ci][co] = Ri[(size_t)l * 4096 + idx];
    }
    float phr = phi[2 * l], phii = phi[2 * l + 1];
    int co = tid & 63, mg = tid >> 6;
    int m0base = mh * 128;
    #pragma unroll 1
    for (int it = 0; it < 32; ++it) {
        int mp = m0base + it * 4 + mg;
        __syncthreads();
        {
            int ci = tid & 63;
            float xr = 0.f, xi = 0.f;
            if (mp < NM) {
                int mm = mp - 127;
                int am = mm < 0 ? -mm : mm;
                size_t idx = (size_t)am * 8192 + (size_t)l * 64 + ci;
                float vr = Xr[idx], vi = Xi[idx];
                if (mm >= 0) { xr = vr; xi = vi; }
                else { float s = (am & 1) ? -1.f : 1.f; xr = s * vr; xi = -s * vi; }
            }
            XsR[mg][ci] = xr; XsI[mg][ci] = xi;
        }
        __syncthreads();
        if (mp < NM) {
            float ar0=0,ar1=0,ar2=0,ar3=0, ai0=0,ai1=0,ai2=0,ai3=0;
            #pragma unroll
            for (int ci = 0; ci < 64; ci += 4) {
                float x0r=XsR[mg][ci+0], x0i=XsI[mg][ci+0];
                float x1r=XsR[mg][ci+1], x1i=XsI[mg][ci+1];
                float x2r=XsR[mg][ci+2], x2i=XsI[mg][ci+2];
                float x3r=XsR[mg][ci+3], x3i=XsI[mg][ci+3];
                float r0=RsR[ci+0][co], q0=RsI[ci+0][co];
                float r1=RsR[ci+1][co], q1=RsI[ci+1][co];
                float r2=RsR[ci+2][co], q2=RsI[ci+2][co];
                float r3=RsR[ci+3][co], q3=RsI[ci+3][co];
                ar0 = fmaf(r0,x0r,fmaf(-q0,x0i,ar0)); ai0 = fmaf(r0,x0i,fmaf(q0,x0r,ai0));
                ar1 = fmaf(r1,x1r,fmaf(-q1,x1i,ar1)); ai1 = fmaf(r1,x1i,fmaf(q1,x1r,ai1));
                ar2 = fmaf(r2,x2r,fmaf(-q2,x2i,ar2)); ai2 = fmaf(r2,x2i,fmaf(q2,x2r,ai2));
                ar3 = fmaf(r3,x3r,fmaf(-q3,x3i,ar3)); ai3 = fmaf(r3,x3i,fmaf(q3,x3r,ai3));
            }
            float ar = (ar0 + ar1) + (ar2 + ar3);
            float ai = (ai0 + ai1) + (ai2 + ai3);
            int mm = mp - 127; int am = mm < 0 ? -mm : mm;
            float sg = (mm < 0 && (am & 1)) ? -1.f : 1.f;
            Or[(size_t)mp * 8192 + (size_t)l * 64 + co] = (f16)(sg * (phr * ar - phii * ai));
            Oi[(size_t)mp * 8192 + (size_t)l * 64 + co] = (f16)(sg * (phr * ai + phii * ar));
        }
    }
}

// ---------------- K6: stage 4 MFMA: G[2m'+u][t][c] = legT[t][l]*O_u[l][c] ---
// grid (mp=255, tt=4). A=leghT[am][tt*64..][l K=128]; B=OT[mp][c][l].
__global__ __launch_bounds__(256) void k_g4(const f16* __restrict__ legT, const f16* __restrict__ OTr,
        const f16* __restrict__ OTi, f16* __restrict__ G) {
    __shared__ f16 As[64][40], Br[64][40], Bi[64][40];
    int mp = blockIdx.x, tt = blockIdx.y, tid = threadIdx.x;
    int mm = mp - 127, am = mm < 0 ? -mm : mm;
    const f16* A  = legT + (size_t)am * (256 * 128) + (size_t)(tt * 64) * 128;
    const f16* B0 = OTr + (size_t)mp * (64 * 128);
    const f16* B1 = OTi + (size_t)mp * (64 * 128);
    f32x4 acc[2][2][2];
    #pragma unroll
    for (int a = 0; a < 2; ++a)
        #pragma unroll
        for (int b = 0; b < 2; ++b)
            #pragma unroll
            for (int c = 0; c < 2; ++c) acc[a][b][c] = (f32x4){0.f, 0.f, 0.f, 0.f};
    int lane = tid & 63, wid = tid >> 6;
    int wm = wid & 1, wn = wid >> 1;
    int fr = lane & 15, g8 = (lane >> 4) * 8;
    int row = tid >> 2, k8 = (tid & 3) * 8;
    for (int kt = am >> 5; kt < 4; ++kt) {
        float4 va = *(const float4*)(A  + (size_t)row * 128 + kt * 32 + k8);
        float4 vr = *(const float4*)(B0 + (size_t)row * 128 + kt * 32 + k8);
        float4 vi = *(const float4*)(B1 + (size_t)row * 128 + kt * 32 + k8);
        __syncthreads();
        *(float4*)&As[row][k8] = va;
        *(float4*)&Br[row][k8] = vr;
        *(float4*)&Bi[row][k8] = vi;
        __syncthreads();
        f16x8 a0 = *(f16x8*)&As[wm * 32 + fr][g8];
        f16x8 a1 = *(f16x8*)&As[wm * 32 + 16 + fr][g8];
        f16x8 r0 = *(f16x8*)&Br[wn * 32 + fr][g8];
        f16x8 r1 = *(f16x8*)&Br[wn * 32 + 16 + fr][g8];
        f16x8 i0 = *(f16x8*)&Bi[wn * 32 + fr][g8];
        f16x8 i1 = *(f16x8*)&Bi[wn * 32 + 16 + fr][g8];
        acc[0][0][0] = __builtin_amdgcn_mfma_f32_16x16x32_f16(a0, r0, acc[0][0][0], 0, 0, 0);
        acc[0][0][1] = __builtin_amdgcn_mfma_f32_16x16x32_f16(a0, r1, acc[0][0][1], 0, 0, 0);
        acc[0][1][0] = __builtin_amdgcn_mfma_f32_16x16x32_f16(a1, r0, acc[0][1][0], 0, 0, 0);
        acc[0][1][1] = __builtin_amdgcn_mfma_f32_16x16x32_f16(a1, r1, acc[0][1][1], 0, 0, 0);
        acc[1][0][0] = __builtin_amdgcn_mfma_f32_16x16x32_f16(a0, i0, acc[1][0][0], 0, 0, 0);
        acc[1][0][1] = __builtin_amdgcn_mfma_f32_16x16x32_f16(a0, i1, acc[1][0][1], 0, 0, 0);
        acc[1][1][0] = __builtin_amdgcn_mfma_f32_16x16x32_f16(a1, i0, acc[1][1][0], 0, 0, 0);
        acc[1][1][1] = __builtin_amdgcn_mfma_f32_16x16x32_f16(a1, i1, acc[1][1][1], 0, 0, 0);
    }
    int rg = (lane >> 4) * 4;
    f16* gr = G + (size_t)(2 * mp) * (256 * 64);
    f16* gi = G + (size_t)(2 * mp + 1) * (256 * 64);
    #pragma unroll
    for (int mf = 0; mf < 2; ++mf)
        #pragma unroll
        for (int nf = 0; nf < 2; ++nf) {
            int c = wn * 32 + nf * 16 + fr;
            #pragma unroll
            for (int r = 0; r < 4; ++r) {
                int tl = tt * 64 + wm * 32 + mf * 16 + rg + r;
                gr[(size_t)tl * 64 + c] = (f16)acc[0][mf][nf][r];
                gi[(size_t)tl * 64 + c] = (f16)acc[1][mf][nf][r];
            }
        }
}

// ---------------- K7: stage 5 MFMA: out[t][p][c] = A5[p][k]*GT[t][c][k] -----
// grid (t=256, pt=8). A=A5[pt*64..][K=512]; B=GT[t][c][512].
__global__ __launch_bounds__(256) void k_g5(const f16* __restrict__ A5, const f16* __restrict__ GT,
                                            float* __restrict__ out) {
    __shared__ f16 As[64][40], Bs[64][40];
    int t = blockIdx.x, pt = blockIdx.y, tid = threadIdx.x;
    const f16* A = A5 + (size_t)(pt * 64) * 512;
    const f16* B = GT + (size_t)t * (64 * 512);
    f32x4 acc[2][2];
    #pragma unroll
    for (int a = 0; a < 2; ++a)
        #pragma unroll
        for (int b = 0; b < 2; ++b) acc[a][b] = (f32x4){0.f, 0.f, 0.f, 0.f};
    int lane = tid & 63, wid = tid >> 6;
    int wm = wid & 1, wn = wid >> 1;
    int fr = lane & 15, g8 = (lane >> 4) * 8;
    int row = tid >> 2, k8 = (tid & 3) * 8;
    for (int kt = 0; kt < 16; ++kt) {
        float4 va = *(const float4*)(A + (size_t)row * 512 + kt * 32 + k8);
        float4 vb = *(const float4*)(B + (size_t)row * 512 + kt * 32 + k8);
        __syncthreads();
        *(float4*)&As[row][k8] = va;
        *(float4*)&Bs[row][k8] = vb;
        __syncthreads();
        f16x8 a0 = *(f16x8*)&As[wm * 32 + fr][g8];
        f16x8 a1 = *(f16x8*)&As[wm * 32 + 16 + fr][g8];
        f16x8 b0 = *(f16x8*)&Bs[wn * 32 + fr][g8];
        f16x8 b1 = *(f16x8*)&Bs[wn * 32 + 16 + fr][g8];
        acc[0][0] = __builtin_amdgcn_mfma_f32_16x16x32_f16(a0, b0, acc[0][0], 0, 0, 0);
        acc[0][1] = __builtin_amdgcn_mfma_f32_16x16x32_f16(a0, b1, acc[0][1], 0, 0, 0);
        acc[1][0] = __builtin_amdgcn_mfma_f32_16x16x32_f16(a1, b0, acc[1][0], 0, 0, 0);
        acc[1][1] = __builtin_amdgcn_mfma_f32_16x16x32_f16(a1, b1, acc[1][1], 0, 0, 0);
    }
    int rg = (lane >> 4) * 4;
    #pragma unroll
    for (int mf = 0; mf < 2; ++mf)
        #pragma unroll
        for (int nf = 0; nf < 2; ++nf) {
            int c = wn * 32 + nf * 16 + fr;
            #pragma unroll
            for (int r = 0; r < 4; ++r) {
                int p = pt * 64 + wm * 32 + mf * 16 + rg + r;
                if (p < NPHI) out[((size_t)t * NPHI + p) * 64 + c] = acc[mf][nf][r];
            }
        }
}

extern "C" void kernel_launch(void* const* d_in, const int* in_sizes, int n_in,
                              void* d_out, int out_size, void* d_ws, size_t ws_size,
                              hipStream_t stream) {
    const float* x    = (const float*)d_in[0];
    const float* temb = (const float*)d_in[1];
    const float* Ar   = (const float*)d_in[2];
    const float* Ai   = (const float*)d_in[3];
    const float* Rr   = (const float*)d_in[4];
    const float* Ri   = (const float*)d_in[5];
    float* out = (float*)d_out;

    char* ws = (char*)d_ws;
    size_t off = 0;
    auto alloc = [&](size_t bytes) -> void* {
        void* p = ws + off;
        off = (off + bytes + 255) & ~(size_t)255;
        return p;
    };
    double* x64  = (double*)alloc(256 * 8);
    double* w64  = (double*)alloc(256 * 8);
    float*  phi  = (float*)alloc(256 * 4);
    f16* legh  = (f16*)alloc((size_t)128 * 128 * 256 * 2);   // 8.39 MB
    f16* leghT = (f16*)alloc((size_t)128 * 256 * 128 * 2);   // 8.39 MB
    f16* cF    = (f16*)alloc((size_t)128 * 512 * 2);
    f16* sF    = (f16*)alloc((size_t)128 * 512 * 2);
    f16* A5    = (f16*)alloc((size_t)512 * 512 * 2);
    f16* R1    = (f16*)alloc((size_t)256 * 64 * 512 * 2);    // 16.78 MB: xh / GT
    f16* R2    = (f16*)alloc((size_t)512 * 256 * 64 * 2);    // 16.78 MB: Fw{R,I,RT,IT} / Gk
    float* Xr  = (float*)alloc((size_t)128 * 128 * 64 * 4);
    float* Xi  = (float*)alloc((size_t)128 * 128 * 64 * 4);
    f16* Or    = (f16*)alloc((size_t)255 * 128 * 64 * 2);
    f16* Oi    = (f16*)alloc((size_t)255 * 128 * 64 * 2);
    f16* OrT   = (f16*)alloc((size_t)255 * 64 * 128 * 2);
    f16* OiT   = (f16*)alloc((size_t)255 * 64 * 128 * 2);
    if (off > ws_size) return;

    f16* xh   = R1;
    f16* GT   = R1;
    f16* FwR  = R2;
    f16* FwI  = R2 + (size_t)2097152;
    f16* FwRT = R2 + (size_t)4194304;
    f16* FwIT = R2 + (size_t)6291456;
    f16* Gk   = R2;

    hipLaunchKernelGGL(k_gl_nodes, dim3(1),         dim3(256), 0, stream, x64, w64);
    hipLaunchKernelGGL(k_leg_h,    dim3(128),       dim3(256), 0, stream, x64, legh);
    hipLaunchKernelGGL(k_tr16,     dim3(128, 8),    dim3(256), 0, stream, legh, leghT, 128, 256);
    hipLaunchKernelGGL(k_tables_h, dim3(1024),      dim3(256), 0, stream, cF, sF, A5);
    hipLaunchKernelGGL(k_phi,      dim3(1),         dim3(128), 0, stream, Ar, Ai, temb, phi);
    hipLaunchKernelGGL(k_convert,  dim3(256, 8),    dim3(256), 0, stream, x, xh);
    hipLaunchKernelGGL(k_g1,       dim3(256, 2),    dim3(256), 0, stream, xh, cF, sF, w64, FwR, FwI);
    hipLaunchKernelGGL(k_tr16,     dim3(128, 4),    dim3(256), 0, stream, FwR, FwRT, 256, 64);
    hipLaunchKernelGGL(k_tr16,     dim3(128, 4),    dim3(256), 0, stream, FwI, FwIT, 256, 64);
    hipLaunchKernelGGL(k_g2,       dim3(128, 2),    dim3(256), 0, stream, legh, FwRT, FwIT, Xr, Xi);
    hipLaunchKernelGGL(k_stage3,   dim3(128, 2),    dim3(256), 0, stream, Xr, Xi, Rr, Ri, phi, Or, Oi);
    hipLaunchKernelGGL(k_tr16,     dim3(255, 2),    dim3(256), 0, stream, Or, OrT, 128, 64);
    hipLaunchKernelGGL(k_tr16,     dim3(255, 2),    dim3(256), 0, stream, Oi, OiT, 128, 64);
    hipMemsetAsync(Gk + (size_t)510 * 16384, 0, (size_t)2 * 16384 * 2, stream);
    hipLaunchKernelGGL(k_g4,       dim3(255, 4),    dim3(256), 0, stream, leghT, OrT, OiT, Gk);
    hipLaunchKernelGGL(k_tr16,     dim3(1, 2048),   dim3(256), 0, stream, Gk, GT, 512, 16384);
    hipLaunchKernelGGL(k_g5,       dim3(256, 8),    dim3(256), 0, stream, A5, GT, out);
}

// Round 4
// 161.356 us; speedup vs baseline: 2.6619x; 1.3310x over previous
//
#include <hip/hip_runtime.h>
#include <math.h>

#ifndef M_PI
#define M_PI 3.14159265358979323846
#endif

typedef _Float16 f16;
typedef _Float16 f16x8 __attribute__((ext_vector_type(8)));
typedef unsigned short u16x8 __attribute__((ext_vector_type(8)));
typedef float f32x4 __attribute__((ext_vector_type(4)));

#define NPHI 511
#define NM   255

// ---------------- K0: Gauss-Legendre nodes/weights (n=256), descending x ----
__global__ void k_gl_nodes(double* x64, double* w64) {
    __shared__ double c1[257], c2[257];
    int i = threadIdx.x;              // 0..255
    for (int k = i; k <= 256; k += 256) {
        if (k >= 2) { c1[k] = (2.0 * k - 1.0) / k; c2[k] = (k - 1.0) / k; }
    }
    __syncthreads();
    const int n = 256;
    double x = cos(M_PI * (i + 0.75) / (n + 0.5));
    double p1 = 0.0, pd = 1.0;
    for (int it = 0; it < 5; ++it) {
        double p0 = 1.0; p1 = x;
        for (int k = 2; k <= n; ++k) {
            double pk = c1[k] * x * p1 - c2[k] * p0;
            p0 = p1; p1 = pk;
        }
        pd = n * (x * p1 - p0) / (x * x - 1.0);
        x -= p1 / pd;
    }
    x64[i] = x;
    w64[i] = 2.0 / ((1.0 - x * x) * pd * pd);
}

// ---------------- K1: assoc. Legendre table legh[m][l][t] fp16 --------------
__global__ void k_leg_h(const double* __restrict__ x64, f16* __restrict__ legh) {
    __shared__ double sa[128], sb[128], sf[128];
    int m = blockIdx.x, t = threadIdx.x;
    if (t < 128) {
        double dl = t, dm = m;
        if (t >= 2) {
            sa[t] = sqrt((4.0 * dl * dl - 1.0) / (dl * dl - dm * dm));
            sb[t] = sqrt(((dl - 1.0) * (dl - 1.0) - dm * dm) / (4.0 * (dl - 1.0) * (dl - 1.0) - 1.0));
        }
        if (t >= 1) sf[t] = -sqrt((2.0 * t + 1.0) / (2.0 * t));
    }
    __syncthreads();
    double x = x64[t];
    double sx = sqrt(fmax(0.0, 1.0 - x * x));
    double pmm = 0.28209479177387814;   // 1/sqrt(4*pi)
    for (int k = 1; k <= m; ++k) pmm *= sf[k] * sx;
    f16* Lm = legh + (size_t)m * (128 * 256);
    for (int l = 0; l < m; ++l) Lm[l * 256 + t] = (f16)0.f;
    Lm[m * 256 + t] = (f16)pmm;
    if (m + 1 < 128) {
        double pl0 = pmm;
        double pl1 = sqrt(2.0 * m + 3.0) * x * pmm;
        Lm[(m + 1) * 256 + t] = (f16)pl1;
        for (int l = m + 2; l < 128; ++l) {
            double pl = sa[l] * (x * pl1 - sb[l] * pl0);
            pl0 = pl1; pl1 = pl;
            Lm[l * 256 + t] = (f16)pl;
        }
    }
}

// ---------------- K2: DFT tables (fp16, float trig) -------------------------
__global__ void k_tables_h(f16* __restrict__ cF, f16* __restrict__ sF, f16* __restrict__ A5) {
    int tid = blockIdx.x * blockDim.x + threadIdx.x;
    const float w0 = (float)(2.0 * M_PI / 511.0);
    const float scale = w0;
    if (tid < 128 * 512) {
        int m = tid >> 9, p = tid & 511;
        float cv = 0.f, sv = 0.f;
        if (p < 511) {
            int r = (p * m) % 511;
            float ang = w0 * (float)r;
            cv = cosf(ang) * scale;
            sv = -sinf(ang) * scale;
        }
        cF[tid] = (f16)cv; sF[tid] = (f16)sv;
    }
    {
        int p = tid >> 9, k = tid & 511;
        float v = 0.f;
        if (p < 511 && k < 510) {
            int mp = k >> 1, mmv = mp - 127;
            int r = (p * mmv) % 511; if (r < 0) r += 511;
            float ang = w0 * (float)r;
            v = (k & 1) ? -sinf(ang) : cosf(ang);
        }
        A5[tid] = (f16)v;
    }
}

// ---------------- K_phi ------------------------------------------------------
__global__ void k_phi(const float* __restrict__ Ar, const float* __restrict__ Ai,
                      const float* __restrict__ te, float* __restrict__ phi) {
    int l = threadIdx.x;  // 0..127
    float sr = 0.f, si = 0.f;
    for (int c = 0; c < 256; ++c) {
        float t = te[c];
        sr = fmaf(Ar[l * 256 + c], t, sr);
        si = fmaf(Ai[l * 256 + c], t, si);
    }
    phi[2 * l] = sr; phi[2 * l + 1] = si;
}

// ---------------- K_prep_R: Rph[l][co][ci] = (Rr+iRi)*(phr+i*phii) f16 ------
__global__ __launch_bounds__(256) void k_prep_R(const float* __restrict__ Rr, const float* __restrict__ Ri,
        const float* __restrict__ phi, f16* __restrict__ Rphr, f16* __restrict__ Rphi) {
    int l = blockIdx.x, tid = threadIdx.x;
    float phr = phi[2 * l], phii = phi[2 * l + 1];
    const float* rr = Rr + (size_t)l * 4096;
    const float* ri = Ri + (size_t)l * 4096;
    #pragma unroll
    for (int e = 0; e < 2; ++e) {
        int base = tid * 8 + e * 2048;
        float4 r0 = *(const float4*)(rr + base), r1 = *(const float4*)(rr + base + 4);
        float4 q0 = *(const float4*)(ri + base), q1 = *(const float4*)(ri + base + 4);
        float rs0 = r0.x, rs1 = r0.y, rs2 = r0.z, rs3 = r0.w;
        float rs4 = r1.x, rs5 = r1.y, rs6 = r1.z, rs7 = r1.w;
        float qs0 = q0.x, qs1 = q0.y, qs2 = q0.z, qs3 = q0.w;
        float qs4 = q1.x, qs5 = q1.y, qs6 = q1.z, qs7 = q1.w;
        __align__(16) f16 hr[8], hi[8];
        hr[0] = (f16)(rs0 * phr - qs0 * phii); hi[0] = (f16)(rs0 * phii + qs0 * phr);
        hr[1] = (f16)(rs1 * phr - qs1 * phii); hi[1] = (f16)(rs1 * phii + qs1 * phr);
        hr[2] = (f16)(rs2 * phr - qs2 * phii); hi[2] = (f16)(rs2 * phii + qs2 * phr);
        hr[3] = (f16)(rs3 * phr - qs3 * phii); hi[3] = (f16)(rs3 * phii + qs3 * phr);
        hr[4] = (f16)(rs4 * phr - qs4 * phii); hi[4] = (f16)(rs4 * phii + qs4 * phr);
        hr[5] = (f16)(rs5 * phr - qs5 * phii); hi[5] = (f16)(rs5 * phii + qs5 * phr);
        hr[6] = (f16)(rs6 * phr - qs6 * phii); hi[6] = (f16)(rs6 * phii + qs6 * phr);
        hr[7] = (f16)(rs7 * phr - qs7 * phii); hi[7] = (f16)(rs7 * phii + qs7 * phr);
        *(float4*)(Rphr + (size_t)l * 4096 + base) = *(float4*)hr;
        *(float4*)(Rphi + (size_t)l * 4096 + base) = *(float4*)hi;
    }
}

// ---------------- K_convert: x[t][p][c] f32 -> xh[t][c][p(512)] f16 ---------
__global__ __launch_bounds__(256) void k_convert(const float* __restrict__ x, f16* __restrict__ xh) {
    __shared__ float Ls[64][68];
    int t = blockIdx.x, pt = blockIdx.y, tid = threadIdx.x;
    int p0 = pt * 64;
    const float* xb = x + (size_t)t * (NPHI * 64);
    #pragma unroll
    for (int e = 0; e < 4; ++e) {
        int idx = tid + e * 256;
        int row = idx >> 4, c4 = (idx & 15) * 4;
        int p = p0 + row;
        float4 v = make_float4(0.f, 0.f, 0.f, 0.f);
        if (p < NPHI) v = *(const float4*)(xb + (size_t)p * 64 + c4);
        *(float4*)&Ls[row][c4] = v;
    }
    __syncthreads();
    #pragma unroll
    for (int e = 0; e < 2; ++e) {
        int idx = tid + e * 256;
        int c = idx >> 3, r8 = (idx & 7) * 8;
        __align__(16) f16 tmp[8];
        #pragma unroll
        for (int j = 0; j < 8; ++j) tmp[j] = (f16)Ls[r8 + j][c];
        *(float4*)(xh + (size_t)t * (64 * 512) + (size_t)c * 512 + p0 + r8) = *(float4*)tmp;
    }
}

// ---------------- generic fp16 transpose [b][R][C] -> [b][C][R] -------------
__global__ __launch_bounds__(256) void k_tr16(const f16* __restrict__ src, f16* __restrict__ dst,
                                              int R, int C) {
    __shared__ f16 Ts[64][72];
    int b = blockIdx.x, tile = blockIdx.y, tid = threadIdx.x;
    int ctiles = C >> 6;
    int rt = tile / ctiles, ct = tile - rt * ctiles;
    const f16* s = src + (size_t)b * R * C + (size_t)(rt * 64) * C + ct * 64;
    #pragma unroll
    for (int e = 0; e < 2; ++e) {
        int idx = tid + e * 256;
        int row = idx >> 3, c8 = (idx & 7) * 8;
        *(float4*)&Ts[row][c8] = *(const float4*)(s + (size_t)row * C + c8);
    }
    __syncthreads();
    f16* d = dst + (size_t)b * R * C + (size_t)(ct * 64) * R + rt * 64;
    #pragma unroll
    for (int e = 0; e < 2; ++e) {
        int idx = tid + e * 256;
        int c = idx >> 3, r8 = (idx & 7) * 8;
        __align__(16) f16 tmp[8];
        #pragma unroll
        for (int j = 0; j < 8; ++j) tmp[j] = Ts[r8 + j][c];
        *(float4*)(d + (size_t)c * R + r8) = *(float4*)tmp;
    }
}

// ---------------- K3: stage 1 MFMA: Fw[m][t][c] = w(t)*T[m][p]*f[p][c] ------
__global__ __launch_bounds__(256) void k_g1(const f16* __restrict__ xh, const f16* __restrict__ cF,
        const f16* __restrict__ sF, const double* __restrict__ w64,
        f16* __restrict__ FwR, f16* __restrict__ FwI) {
    __shared__ f16 Ac[64][40], An[64][40], Bs[64][40];
    int t = blockIdx.x, mt = blockIdx.y, tid = threadIdx.x;
    const f16* A0 = cF + (size_t)(mt * 64) * 512;
    const f16* A1 = sF + (size_t)(mt * 64) * 512;
    const f16* B  = xh + (size_t)t * (64 * 512);
    f32x4 acc[2][2][2];  // [tab][mf][nf]
    #pragma unroll
    for (int a = 0; a < 2; ++a)
        #pragma unroll
        for (int b = 0; b < 2; ++b)
            #pragma unroll
            for (int c = 0; c < 2; ++c) acc[a][b][c] = (f32x4){0.f, 0.f, 0.f, 0.f};
    int lane = tid & 63, wid = tid >> 6;
    int wm = wid & 1, wn = wid >> 1;
    int fr = lane & 15, g8 = (lane >> 4) * 8;
    int row = tid >> 2, k8 = (tid & 3) * 8;
    for (int kt = 0; kt < 16; ++kt) {
        float4 va = *(const float4*)(A0 + (size_t)row * 512 + kt * 32 + k8);
        float4 vn = *(const float4*)(A1 + (size_t)row * 512 + kt * 32 + k8);
        float4 vb = *(const float4*)(B  + (size_t)row * 512 + kt * 32 + k8);
        __syncthreads();
        *(float4*)&Ac[row][k8] = va;
        *(float4*)&An[row][k8] = vn;
        *(float4*)&Bs[row][k8] = vb;
        __syncthreads();
        f16x8 b0 = *(f16x8*)&Bs[wn * 32 + fr][g8];
        f16x8 b1 = *(f16x8*)&Bs[wn * 32 + 16 + fr][g8];
        f16x8 a0 = *(f16x8*)&Ac[wm * 32 + fr][g8];
        f16x8 a1 = *(f16x8*)&Ac[wm * 32 + 16 + fr][g8];
        f16x8 s0 = *(f16x8*)&An[wm * 32 + fr][g8];
        f16x8 s1 = *(f16x8*)&An[wm * 32 + 16 + fr][g8];
        acc[0][0][0] = __builtin_amdgcn_mfma_f32_16x16x32_f16(a0, b0, acc[0][0][0], 0, 0, 0);
        acc[0][0][1] = __builtin_amdgcn_mfma_f32_16x16x32_f16(a0, b1, acc[0][0][1], 0, 0, 0);
        acc[0][1][0] = __builtin_amdgcn_mfma_f32_16x16x32_f16(a1, b0, acc[0][1][0], 0, 0, 0);
        acc[0][1][1] = __builtin_amdgcn_mfma_f32_16x16x32_f16(a1, b1, acc[0][1][1], 0, 0, 0);
        acc[1][0][0] = __builtin_amdgcn_mfma_f32_16x16x32_f16(s0, b0, acc[1][0][0], 0, 0, 0);
        acc[1][0][1] = __builtin_amdgcn_mfma_f32_16x16x32_f16(s0, b1, acc[1][0][1], 0, 0, 0);
        acc[1][1][0] = __builtin_amdgcn_mfma_f32_16x16x32_f16(s1, b0, acc[1][1][0], 0, 0, 0);
        acc[1][1][1] = __builtin_amdgcn_mfma_f32_16x16x32_f16(s1, b1, acc[1][1][1], 0, 0, 0);
    }
    float wf = (float)w64[t];
    int rg = (lane >> 4) * 4;
    #pragma unroll
    for (int mf = 0; mf < 2; ++mf)
        #pragma unroll
        for (int nf = 0; nf < 2; ++nf) {
            int c = wn * 32 + nf * 16 + fr;
            #pragma unroll
            for (int r = 0; r < 4; ++r) {
                int m = mt * 64 + wm * 32 + mf * 16 + rg + r;
                FwR[((size_t)m * 256 + t) * 64 + c] = (f16)(acc[0][mf][nf][r] * wf);
                FwI[((size_t)m * 256 + t) * 64 + c] = (f16)(acc[1][mf][nf][r] * wf);
            }
        }
}

// ---------------- K4: stage 2 MFMA: Xh[m][l][c] = leg[l][t]*Fw[t][c] (f16 out)
__global__ __launch_bounds__(256) void k_g2(const f16* __restrict__ legh, const f16* __restrict__ BTr,
        const f16* __restrict__ BTi, f16* __restrict__ Xhr, f16* __restrict__ Xhi) {
    __shared__ f16 As[64][40], Br[64][40], Bi[64][40];
    int m = blockIdx.x, lt = blockIdx.y, tid = threadIdx.x;
    const f16* A  = legh + (size_t)m * (128 * 256) + (size_t)(lt * 64) * 256;
    const f16* B0 = BTr + (size_t)m * (64 * 256);
    const f16* B1 = BTi + (size_t)m * (64 * 256);
    f32x4 acc[2][2][2];  // [bsel][mf][nf]
    #pragma unroll
    for (int a = 0; a < 2; ++a)
        #pragma unroll
        for (int b = 0; b < 2; ++b)
            #pragma unroll
            for (int c = 0; c < 2; ++c) acc[a][b][c] = (f32x4){0.f, 0.f, 0.f, 0.f};
    int lane = tid & 63, wid = tid >> 6;
    int wm = wid & 1, wn = wid >> 1;
    int fr = lane & 15, g8 = (lane >> 4) * 8;
    int row = tid >> 2, k8 = (tid & 3) * 8;
    for (int kt = 0; kt < 8; ++kt) {
        float4 va = *(const float4*)(A  + (size_t)row * 256 + kt * 32 + k8);
        float4 vr = *(const float4*)(B0 + (size_t)row * 256 + kt * 32 + k8);
        float4 vi = *(const float4*)(B1 + (size_t)row * 256 + kt * 32 + k8);
        __syncthreads();
        *(float4*)&As[row][k8] = va;
        *(float4*)&Br[row][k8] = vr;
        *(float4*)&Bi[row][k8] = vi;
        __syncthreads();
        f16x8 a0 = *(f16x8*)&As[wm * 32 + fr][g8];
        f16x8 a1 = *(f16x8*)&As[wm * 32 + 16 + fr][g8];
        f16x8 r0 = *(f16x8*)&Br[wn * 32 + fr][g8];
        f16x8 r1 = *(f16x8*)&Br[wn * 32 + 16 + fr][g8];
        f16x8 i0 = *(f16x8*)&Bi[wn * 32 + fr][g8];
        f16x8 i1 = *(f16x8*)&Bi[wn * 32 + 16 + fr][g8];
        acc[0][0][0] = __builtin_amdgcn_mfma_f32_16x16x32_f16(a0, r0, acc[0][0][0], 0, 0, 0);
        acc[0][0][1] = __builtin_amdgcn_mfma_f32_16x16x32_f16(a0, r1, acc[0][0][1], 0, 0, 0);
        acc[0][1][0] = __builtin_amdgcn_mfma_f32_16x16x32_f16(a1, r0, acc[0][1][0], 0, 0, 0);
        acc[0][1][1] = __builtin_amdgcn_mfma_f32_16x16x32_f16(a1, r1, acc[0][1][1], 0, 0, 0);
        acc[1][0][0] = __builtin_amdgcn_mfma_f32_16x16x32_f16(a0, i0, acc[1][0][0], 0, 0, 0);
        acc[1][0][1] = __builtin_amdgcn_mfma_f32_16x16x32_f16(a0, i1, acc[1][0][1], 0, 0, 0);
        acc[1][1][0] = __builtin_amdgcn_mfma_f32_16x16x32_f16(a1, i0, acc[1][1][0], 0, 0, 0);
        acc[1][1][1] = __builtin_amdgcn_mfma_f32_16x16x32_f16(a1, i1, acc[1][1][1], 0, 0, 0);
    }
    int rg = (lane >> 4) * 4;
    #pragma unroll
    for (int mf = 0; mf < 2; ++mf)
        #pragma unroll
        for (int nf = 0; nf < 2; ++nf) {
            int c = wn * 32 + nf * 16 + fr;
            #pragma unroll
            for (int r = 0; r < 4; ++r) {
                int l = lt * 64 + wm * 32 + mf * 16 + rg + r;
                Xhr[(size_t)m * 8192 + l * 64 + c] = (f16)acc[0][mf][nf][r];
                Xhi[(size_t)m * 8192 + l * 64 + c] = (f16)acc[1][mf][nf][r];
            }
        }
}

// ---------------- K5: stage 3 MFMA: Out[m'][co] = Xe[m'][ci] . Rph[co][ci] --
// Xe[m'] = X[m] (m>=0) or conj(X[|m|]) (m<0); (-1)^m factors cancel with stage-4 sign.
// grid (l=128, mt=4), 256 thr.
__global__ __launch_bounds__(256) void k_s3m(const f16* __restrict__ Xhr, const f16* __restrict__ Xhi,
        const f16* __restrict__ Rphr, const f16* __restrict__ Rphi,
        f16* __restrict__ Or, f16* __restrict__ Oi) {
    __shared__ f16 Ars[64][72], Ais[64][72], Ans[64][72];
    int l = blockIdx.x, mt = blockIdx.y, tid = threadIdx.x;
    {
        int arow = tid >> 2;
        int mp = mt * 64 + arow;
        int mmv = mp - 127, am = mmv < 0 ? -mmv : mmv;
        unsigned short cj = (mmv < 0) ? 0x8000 : 0;
        u16x8 cjv = {cj, cj, cj, cj, cj, cj, cj, cj};
        u16x8 ngv = {0x8000, 0x8000, 0x8000, 0x8000, 0x8000, 0x8000, 0x8000, 0x8000};
        #pragma unroll
        for (int e = 0; e < 2; ++e) {
            int ci8 = (tid & 3) * 8 + e * 32;
            u16x8 vr = {0, 0, 0, 0, 0, 0, 0, 0};
            u16x8 vi = {0, 0, 0, 0, 0, 0, 0, 0};
            if (mp < 255) {
                vr = *(const u16x8*)(Xhr + (size_t)am * 8192 + l * 64 + ci8);
                vi = *(const u16x8*)(Xhi + (size_t)am * 8192 + l * 64 + ci8);
            }
            u16x8 vic = vi ^ cjv;       // conjugated imag
            u16x8 vin = vic ^ ngv;      // negated
            *(u16x8*)&Ars[arow][ci8] = vr;
            *(u16x8*)&Ais[arow][ci8] = vic;
            *(u16x8*)&Ans[arow][ci8] = vin;
        }
    }
    __syncthreads();
    int lane = tid & 63, wid = tid >> 6;
    int wm = wid & 1, wn = wid >> 1;
    int fr = lane & 15, g8 = (lane >> 4) * 8;
    const f16* Bre = Rphr + (size_t)l * 4096;
    const f16* Bim = Rphi + (size_t)l * 4096;
    f32x4 accr[2][2], acci[2][2];
    #pragma unroll
    for (int a = 0; a < 2; ++a)
        #pragma unroll
        for (int b = 0; b < 2; ++b) { accr[a][b] = (f32x4){0.f,0.f,0.f,0.f}; acci[a][b] = (f32x4){0.f,0.f,0.f,0.f}; }
    #pragma unroll
    for (int ks = 0; ks < 2; ++ks) {
        int ko = ks * 32 + g8;
        f16x8 ar0 = *(f16x8*)&Ars[wm * 32 + fr][ko];
        f16x8 ar1 = *(f16x8*)&Ars[wm * 32 + 16 + fr][ko];
        f16x8 ai0 = *(f16x8*)&Ais[wm * 32 + fr][ko];
        f16x8 ai1 = *(f16x8*)&Ais[wm * 32 + 16 + fr][ko];
        f16x8 an0 = *(f16x8*)&Ans[wm * 32 + fr][ko];
        f16x8 an1 = *(f16x8*)&Ans[wm * 32 + 16 + fr][ko];
        #pragma unroll
        for (int nf = 0; nf < 2; ++nf) {
            int brow = wn * 32 + nf * 16 + fr;
            f16x8 br = *(const f16x8*)(Bre + (size_t)brow * 64 + ko);
            f16x8 bi = *(const f16x8*)(Bim + (size_t)brow * 64 + ko);
            accr[0][nf] = __builtin_amdgcn_mfma_f32_16x16x32_f16(ar0, br, accr[0][nf], 0, 0, 0);
            accr[0][nf] = __builtin_amdgcn_mfma_f32_16x16x32_f16(an0, bi, accr[0][nf], 0, 0, 0);
            acci[0][nf] = __builtin_amdgcn_mfma_f32_16x16x32_f16(ar0, bi, acci[0][nf], 0, 0, 0);
            acci[0][nf] = __builtin_amdgcn_mfma_f32_16x16x32_f16(ai0, br, acci[0][nf], 0, 0, 0);
            accr[1][nf] = __builtin_amdgcn_mfma_f32_16x16x32_f16(ar1, br, accr[1][nf], 0, 0, 0);
            accr[1][nf] = __builtin_amdgcn_mfma_f32_16x16x32_f16(an1, bi, accr[1][nf], 0, 0, 0);
            acci[1][nf] = __builtin_amdgcn_mfma_f32_16x16x32_f16(ar1, bi, acci[1][nf], 0, 0, 0);
            acci[1][nf] = __builtin_amdgcn_mfma_f32_16x16x32_f16(ai1, br, acci[1][nf], 0, 0, 0);
        }
    }
    int rg = (lane >> 4) * 4;
    #pragma unroll
    for (int mf = 0; mf < 2; ++mf)
        #pragma unroll
        for (int nf = 0; nf < 2; ++nf) {
            int co = wn * 32 + nf * 16 + fr;
            #pragma unroll
            for (int r = 0; r < 4; ++r) {
                int mp = mt * 64 + wm * 32 + mf * 16 + rg + r;
                if (mp < 255) {
                    Or[(size_t)mp * 8192 + l * 64 + co] = (f16)accr[mf][nf][r];
                    Oi[(size_t)mp * 8192 + l * 64 + co] = (f16)acci[mf][nf][r];
                }
            }
        }
}

// ---------------- K6: stage 4 MFMA: G[2m'+u][t][c] = legT[t][l]*O_u[l][c] ---
__global__ __launch_bounds__(256) void k_g4(const f16* __restrict__ legT, const f16* __restrict__ OTr,
        const f16* __restrict__ OTi, f16* __restrict__ G) {
    __shared__ f16 As[64][40], Br[64][40], Bi[64][40];
    int mp = blockIdx.x, tt = blockIdx.y, tid = threadIdx.x;
    int mmv = mp - 127, am = mmv < 0 ? -mmv : mmv;
    const f16* A  = legT + (size_t)am * (256 * 128) + (size_t)(tt * 64) * 128;
    const f16* B0 = OTr + (size_t)mp * (64 * 128);
    const f16* B1 = OTi + (size_t)mp * (64 * 128);
    f32x4 acc[2][2][2];
    #pragma unroll
    for (int a = 0; a < 2; ++a)
        #pragma unroll
        for (int b = 0; b < 2; ++b)
            #pragma unroll
            for (int c = 0; c < 2; ++c) acc[a][b][c] = (f32x4){0.f, 0.f, 0.f, 0.f};
    int lane = tid & 63, wid = tid >> 6;
    int wm = wid & 1, wn = wid >> 1;
    int fr = lane & 15, g8 = (lane >> 4) * 8;
    int row = tid >> 2, k8 = (tid & 3) * 8;
    for (int kt = am >> 5; kt < 4; ++kt) {
        float4 va = *(const float4*)(A  + (size_t)row * 128 + kt * 32 + k8);
        float4 vr = *(const float4*)(B0 + (size_t)row * 128 + kt * 32 + k8);
        float4 vi = *(const float4*)(B1 + (size_t)row * 128 + kt * 32 + k8);
        __syncthreads();
        *(float4*)&As[row][k8] = va;
        *(float4*)&Br[row][k8] = vr;
        *(float4*)&Bi[row][k8] = vi;
        __syncthreads();
        f16x8 a0 = *(f16x8*)&As[wm * 32 + fr][g8];
        f16x8 a1 = *(f16x8*)&As[wm * 32 + 16 + fr][g8];
        f16x8 r0 = *(f16x8*)&Br[wn * 32 + fr][g8];
        f16x8 r1 = *(f16x8*)&Br[wn * 32 + 16 + fr][g8];
        f16x8 i0 = *(f16x8*)&Bi[wn * 32 + fr][g8];
        f16x8 i1 = *(f16x8*)&Bi[wn * 32 + 16 + fr][g8];
        acc[0][0][0] = __builtin_amdgcn_mfma_f32_16x16x32_f16(a0, r0, acc[0][0][0], 0, 0, 0);
        acc[0][0][1] = __builtin_amdgcn_mfma_f32_16x16x32_f16(a0, r1, acc[0][0][1], 0, 0, 0);
        acc[0][1][0] = __builtin_amdgcn_mfma_f32_16x16x32_f16(a1, r0, acc[0][1][0], 0, 0, 0);
        acc[0][1][1] = __builtin_amdgcn_mfma_f32_16x16x32_f16(a1, r1, acc[0][1][1], 0, 0, 0);
        acc[1][0][0] = __builtin_amdgcn_mfma_f32_16x16x32_f16(a0, i0, acc[1][0][0], 0, 0, 0);
        acc[1][0][1] = __builtin_amdgcn_mfma_f32_16x16x32_f16(a0, i1, acc[1][0][1], 0, 0, 0);
        acc[1][1][0] = __builtin_amdgcn_mfma_f32_16x16x32_f16(a1, i0, acc[1][1][0], 0, 0, 0);
        acc[1][1][1] = __builtin_amdgcn_mfma_f32_16x16x32_f16(a1, i1, acc[1][1][1], 0, 0, 0);
    }
    int rg = (lane >> 4) * 4;
    f16* gr = G + (size_t)(2 * mp) * (256 * 64);
    f16* gi = G + (size_t)(2 * mp + 1) * (256 * 64);
    #pragma unroll
    for (int mf = 0; mf < 2; ++mf)
        #pragma unroll
        for (int nf = 0; nf < 2; ++nf) {
            int c = wn * 32 + nf * 16 + fr;
            #pragma unroll
            for (int r = 0; r < 4; ++r) {
                int tl = tt * 64 + wm * 32 + mf * 16 + rg + r;
                gr[(size_t)tl * 64 + c] = (f16)acc[0][mf][nf][r];
                gi[(size_t)tl * 64 + c] = (f16)acc[1][mf][nf][r];
            }
        }
}

// ---------------- K7: stage 5 MFMA: out[t][p][c] = A5[p][k]*GT[t][c][k] -----
__global__ __launch_bounds__(256) void k_g5(const f16* __restrict__ A5, const f16* __restrict__ GT,
                                            float* __restrict__ out) {
    __shared__ f16 As[64][40], Bs[64][40];
    int t = blockIdx.x, pt = blockIdx.y, tid = threadIdx.x;
    const f16* A = A5 + (size_t)(pt * 64) * 512;
    const f16* B = GT + (size_t)t * (64 * 512);
    f32x4 acc[2][2];
    #pragma unroll
    for (int a = 0; a < 2; ++a)
        #pragma unroll
        for (int b = 0; b < 2; ++b) acc[a][b] = (f32x4){0.f, 0.f, 0.f, 0.f};
    int lane = tid & 63, wid = tid >> 6;
    int wm = wid & 1, wn = wid >> 1;
    int fr = lane & 15, g8 = (lane >> 4) * 8;
    int row = tid >> 2, k8 = (tid & 3) * 8;
    for (int kt = 0; kt < 16; ++kt) {
        float4 va = *(const float4*)(A + (size_t)row * 512 + kt * 32 + k8);
        float4 vb = *(const float4*)(B + (size_t)row * 512 + kt * 32 + k8);
        __syncthreads();
        *(float4*)&As[row][k8] = va;
        *(float4*)&Bs[row][k8] = vb;
        __syncthreads();
        f16x8 a0 = *(f16x8*)&As[wm * 32 + fr][g8];
        f16x8 a1 = *(f16x8*)&As[wm * 32 + 16 + fr][g8];
        f16x8 b0 = *(f16x8*)&Bs[wn * 32 + fr][g8];
        f16x8 b1 = *(f16x8*)&Bs[wn * 32 + 16 + fr][g8];
        acc[0][0] = __builtin_amdgcn_mfma_f32_16x16x32_f16(a0, b0, acc[0][0], 0, 0, 0);
        acc[0][1] = __builtin_amdgcn_mfma_f32_16x16x32_f16(a0, b1, acc[0][1], 0, 0, 0);
        acc[1][0] = __builtin_amdgcn_mfma_f32_16x16x32_f16(a1, b0, acc[1][0], 0, 0, 0);
        acc[1][1] = __builtin_amdgcn_mfma_f32_16x16x32_f16(a1, b1, acc[1][1], 0, 0, 0);
    }
    int rg = (lane >> 4) * 4;
    #pragma unroll
    for (int mf = 0; mf < 2; ++mf)
        #pragma unroll
        for (int nf = 0; nf < 2; ++nf) {
            int c = wn * 32 + nf * 16 + fr;
            #pragma unroll
            for (int r = 0; r < 4; ++r) {
                int p = pt * 64 + wm * 32 + mf * 16 + rg + r;
                if (p < NPHI) out[((size_t)t * NPHI + p) * 64 + c] = acc[mf][nf][r];
            }
        }
}

extern "C" void kernel_launch(void* const* d_in, const int* in_sizes, int n_in,
                              void* d_out, int out_size, void* d_ws, size_t ws_size,
                              hipStream_t stream) {
    const float* x    = (const float*)d_in[0];
    const float* temb = (const float*)d_in[1];
    const float* Ar   = (const float*)d_in[2];
    const float* Ai   = (const float*)d_in[3];
    const float* Rr   = (const float*)d_in[4];
    const float* Ri   = (const float*)d_in[5];
    float* out = (float*)d_out;

    char* ws = (char*)d_ws;
    size_t off = 0;
    auto alloc = [&](size_t bytes) -> void* {
        void* p = ws + off;
        off = (off + bytes + 255) & ~(size_t)255;
        return p;
    };
    double* x64  = (double*)alloc(256 * 8);
    double* w64  = (double*)alloc(256 * 8);
    float*  phi  = (float*)alloc(256 * 4);
    f16* legh  = (f16*)alloc((size_t)128 * 128 * 256 * 2);   // 8.39 MB
    f16* leghT = (f16*)alloc((size_t)128 * 256 * 128 * 2);   // 8.39 MB
    f16* cF    = (f16*)alloc((size_t)128 * 512 * 2);
    f16* sF    = (f16*)alloc((size_t)128 * 512 * 2);
    f16* A5    = (f16*)alloc((size_t)512 * 512 * 2);
    f16* R1    = (f16*)alloc((size_t)256 * 64 * 512 * 2);    // 16.78 MB: xh / GT
    f16* R2    = (f16*)alloc((size_t)512 * 256 * 64 * 2);    // 16.78 MB: Fw{R,I,RT,IT} / Gk
    f16* Xhr   = (f16*)alloc((size_t)128 * 128 * 64 * 2);    // 2.1 MB
    f16* Xhi   = (f16*)alloc((size_t)128 * 128 * 64 * 2);
    f16* Rphr  = (f16*)alloc((size_t)128 * 64 * 64 * 2);     // 1.05 MB
    f16* Rphi  = (f16*)alloc((size_t)128 * 64 * 64 * 2);
    f16* Or    = (f16*)alloc((size_t)255 * 128 * 64 * 2);
    f16* Oi    = (f16*)alloc((size_t)255 * 128 * 64 * 2);
    f16* OrT   = (f16*)alloc((size_t)255 * 64 * 128 * 2);
    f16* OiT   = (f16*)alloc((size_t)255 * 64 * 128 * 2);
    if (off > ws_size) return;

    f16* xh   = R1;
    f16* GT   = R1;
    f16* FwR  = R2;
    f16* FwI  = R2 + (size_t)2097152;
    f16* FwRT = R2 + (size_t)4194304;
    f16* FwIT = R2 + (size_t)6291456;
    f16* Gk   = R2;

    hipLaunchKernelGGL(k_gl_nodes, dim3(1),         dim3(256), 0, stream, x64, w64);
    hipLaunchKernelGGL(k_leg_h,    dim3(128),       dim3(256), 0, stream, x64, legh);
    hipLaunchKernelGGL(k_tr16,     dim3(128, 8),    dim3(256), 0, stream, legh, leghT, 128, 256);
    hipLaunchKernelGGL(k_tables_h, dim3(1024),      dim3(256), 0, stream, cF, sF, A5);
    hipLaunchKernelGGL(k_phi,      dim3(1),         dim3(128), 0, stream, Ar, Ai, temb, phi);
    hipLaunchKernelGGL(k_prep_R,   dim3(128),       dim3(256), 0, stream, Rr, Ri, phi, Rphr, Rphi);
    hipLaunchKernelGGL(k_convert,  dim3(256, 8),    dim3(256), 0, stream, x, xh);
    hipLaunchKernelGGL(k_g1,       dim3(256, 2),    dim3(256), 0, stream, xh, cF, sF, w64, FwR, FwI);
    hipLaunchKernelGGL(k_tr16,     dim3(128, 4),    dim3(256), 0, stream, FwR, FwRT, 256, 64);
    hipLaunchKernelGGL(k_tr16,     dim3(128, 4),    dim3(256), 0, stream, FwI, FwIT, 256, 64);
    hipLaunchKernelGGL(k_g2,       dim3(128, 2),    dim3(256), 0, stream, legh, FwRT, FwIT, Xhr, Xhi);
    hipLaunchKernelGGL(k_s3m,      dim3(128, 4),    dim3(256), 0, stream, Xhr, Xhi, Rphr, Rphi, Or, Oi);
    hipLaunchKernelGGL(k_tr16,     dim3(255, 2),    dim3(256), 0, stream, Or, OrT, 128, 64);
    hipLaunchKernelGGL(k_tr16,     dim3(255, 2),    dim3(256), 0, stream, Oi, OiT, 128, 64);
    hipMemsetAsync(Gk + (size_t)510 * 16384, 0, (size_t)2 * 16384 * 2, stream);
    hipLaunchKernelGGL(k_g4,       dim3(255, 4),    dim3(256), 0, stream, leghT, OrT, OiT, Gk);
    hipLaunchKernelGGL(k_tr16,     dim3(1, 2048),   dim3(256), 0, stream, Gk, GT, 512, 16384);
    hipLaunchKernelGGL(k_g5,       dim3(256, 8),    dim3(256), 0, stream, A5, GT, out);
}

// Round 5
// 155.537 us; speedup vs baseline: 2.7615x; 1.0374x over previous
//
#include <hip/hip_runtime.h>
#include <math.h>

#ifndef M_PI
#define M_PI 3.14159265358979323846
#endif

typedef _Float16 f16;
typedef _Float16 f16x8 __attribute__((ext_vector_type(8)));
typedef unsigned short u16x8 __attribute__((ext_vector_type(8)));
typedef float f32x4 __attribute__((ext_vector_type(4)));

#define NPHI 511
#define NM   255

// ---------------- K0: Gauss-Legendre nodes/weights (n=256), descending x ----
__global__ void k_gl_nodes(double* x64, double* w64) {
    __shared__ double c1[257], c2[257];
    int i = threadIdx.x;              // 0..255
    for (int k = i; k <= 256; k += 256) {
        if (k >= 2) { c1[k] = (2.0 * k - 1.0) / k; c2[k] = (k - 1.0) / k; }
    }
    __syncthreads();
    const int n = 256;
    double x = cos(M_PI * (i + 0.75) / (n + 0.5));
    double p1 = 0.0, pd = 1.0;
    for (int it = 0; it < 5; ++it) {
        double p0 = 1.0; p1 = x;
        for (int k = 2; k <= n; ++k) {
            double pk = c1[k] * x * p1 - c2[k] * p0;
            p0 = p1; p1 = pk;
        }
        pd = n * (x * p1 - p0) / (x * x - 1.0);
        x -= p1 / pd;
    }
    x64[i] = x;
    w64[i] = 2.0 / ((1.0 - x * x) * pd * pd);
}

// ---------------- K1: assoc. Legendre table legh[m][l][t] fp16 --------------
__global__ void k_leg_h(const double* __restrict__ x64, f16* __restrict__ legh) {
    __shared__ double sa[128], sb[128], sf[128];
    int m = blockIdx.x, t = threadIdx.x;
    if (t < 128) {
        double dl = t, dm = m;
        if (t >= 2) {
            sa[t] = sqrt((4.0 * dl * dl - 1.0) / (dl * dl - dm * dm));
            sb[t] = sqrt(((dl - 1.0) * (dl - 1.0) - dm * dm) / (4.0 * (dl - 1.0) * (dl - 1.0) - 1.0));
        }
        if (t >= 1) sf[t] = -sqrt((2.0 * t + 1.0) / (2.0 * t));
    }
    __syncthreads();
    double x = x64[t];
    double sx = sqrt(fmax(0.0, 1.0 - x * x));
    double pmm = 0.28209479177387814;   // 1/sqrt(4*pi)
    for (int k = 1; k <= m; ++k) pmm *= sf[k] * sx;
    f16* Lm = legh + (size_t)m * (128 * 256);
    for (int l = 0; l < m; ++l) Lm[l * 256 + t] = (f16)0.f;
    Lm[m * 256 + t] = (f16)pmm;
    if (m + 1 < 128) {
        double pl0 = pmm;
        double pl1 = sqrt(2.0 * m + 3.0) * x * pmm;
        Lm[(m + 1) * 256 + t] = (f16)pl1;
        for (int l = m + 2; l < 128; ++l) {
            double pl = sa[l] * (x * pl1 - sb[l] * pl0);
            pl0 = pl1; pl1 = pl;
            Lm[l * 256 + t] = (f16)pl;
        }
    }
}

// ---------------- K2: DFT tables (fp16, float trig) -------------------------
// A5 columns k=510,511 are EXACTLY ZERO -> G pad rows need no zeroing.
__global__ void k_tables_h(f16* __restrict__ cF, f16* __restrict__ sF, f16* __restrict__ A5) {
    int tid = blockIdx.x * blockDim.x + threadIdx.x;
    const float w0 = (float)(2.0 * M_PI / 511.0);
    const float scale = w0;
    if (tid < 128 * 512) {
        int m = tid >> 9, p = tid & 511;
        float cv = 0.f, sv = 0.f;
        if (p < 511) {
            int r = (p * m) % 511;
            float ang = w0 * (float)r;
            cv = cosf(ang) * scale;
            sv = -sinf(ang) * scale;
        }
        cF[tid] = (f16)cv; sF[tid] = (f16)sv;
    }
    {
        int p = tid >> 9, k = tid & 511;
        float v = 0.f;
        if (p < 511 && k < 510) {
            int mp = k >> 1, mmv = mp - 127;
            int r = (p * mmv) % 511; if (r < 0) r += 511;
            float ang = w0 * (float)r;
            v = (k & 1) ? -sinf(ang) : cosf(ang);
        }
        A5[tid] = (f16)v;
    }
}

// ---------------- K_phi ------------------------------------------------------
__global__ void k_phi(const float* __restrict__ Ar, const float* __restrict__ Ai,
                      const float* __restrict__ te, float* __restrict__ phi) {
    int l = threadIdx.x;  // 0..127
    float sr = 0.f, si = 0.f;
    for (int c = 0; c < 256; ++c) {
        float t = te[c];
        sr = fmaf(Ar[l * 256 + c], t, sr);
        si = fmaf(Ai[l * 256 + c], t, si);
    }
    phi[2 * l] = sr; phi[2 * l + 1] = si;
}

// ---------------- K_prep_R: Rph[l][co][ci] = (Rr+iRi)*(phr+i*phii) f16 ------
__global__ __launch_bounds__(256) void k_prep_R(const float* __restrict__ Rr, const float* __restrict__ Ri,
        const float* __restrict__ phi, f16* __restrict__ Rphr, f16* __restrict__ Rphi) {
    int l = blockIdx.x, tid = threadIdx.x;
    float phr = phi[2 * l], phii = phi[2 * l + 1];
    const float* rr = Rr + (size_t)l * 4096;
    const float* ri = Ri + (size_t)l * 4096;
    #pragma unroll
    for (int e = 0; e < 2; ++e) {
        int base = tid * 8 + e * 2048;
        float4 r0 = *(const float4*)(rr + base), r1 = *(const float4*)(rr + base + 4);
        float4 q0 = *(const float4*)(ri + base), q1 = *(const float4*)(ri + base + 4);
        __align__(16) f16 hr[8], hi[8];
        hr[0] = (f16)(r0.x * phr - q0.x * phii); hi[0] = (f16)(r0.x * phii + q0.x * phr);
        hr[1] = (f16)(r0.y * phr - q0.y * phii); hi[1] = (f16)(r0.y * phii + q0.y * phr);
        hr[2] = (f16)(r0.z * phr - q0.z * phii); hi[2] = (f16)(r0.z * phii + q0.z * phr);
        hr[3] = (f16)(r0.w * phr - q0.w * phii); hi[3] = (f16)(r0.w * phii + q0.w * phr);
        hr[4] = (f16)(r1.x * phr - q1.x * phii); hi[4] = (f16)(r1.x * phii + q1.x * phr);
        hr[5] = (f16)(r1.y * phr - q1.y * phii); hi[5] = (f16)(r1.y * phii + q1.y * phr);
        hr[6] = (f16)(r1.z * phr - q1.z * phii); hi[6] = (f16)(r1.z * phii + q1.z * phr);
        hr[7] = (f16)(r1.w * phr - q1.w * phii); hi[7] = (f16)(r1.w * phii + q1.w * phr);
        *(float4*)(Rphr + (size_t)l * 4096 + base) = *(float4*)hr;
        *(float4*)(Rphi + (size_t)l * 4096 + base) = *(float4*)hi;
    }
}

// ---------------- K_convert: x[t][p][c] f32 -> xh[t][c][p(512)] f16 ---------
__global__ __launch_bounds__(256) void k_convert(const float* __restrict__ x, f16* __restrict__ xh) {
    __shared__ float Ls[64][68];
    int t = blockIdx.x, pt = blockIdx.y, tid = threadIdx.x;
    int p0 = pt * 64;
    const float* xb = x + (size_t)t * (NPHI * 64);
    #pragma unroll
    for (int e = 0; e < 4; ++e) {
        int idx = tid + e * 256;
        int row = idx >> 4, c4 = (idx & 15) * 4;
        int p = p0 + row;
        float4 v = make_float4(0.f, 0.f, 0.f, 0.f);
        if (p < NPHI) v = *(const float4*)(xb + (size_t)p * 64 + c4);
        *(float4*)&Ls[row][c4] = v;
    }
    __syncthreads();
    #pragma unroll
    for (int e = 0; e < 2; ++e) {
        int idx = tid + e * 256;
        int c = idx >> 3, r8 = (idx & 7) * 8;
        __align__(16) f16 tmp[8];
        #pragma unroll
        for (int j = 0; j < 8; ++j) tmp[j] = (f16)Ls[r8 + j][c];
        *(float4*)(xh + (size_t)t * (64 * 512) + (size_t)c * 512 + p0 + r8) = *(float4*)tmp;
    }
}

// ---------------- generic fp16 transpose [b][R][C] -> [b][C][R] -------------
__device__ __forceinline__ void tr16_body(const f16* __restrict__ s, f16* __restrict__ d,
                                          int R, int C, int rt, int ct, int tid) {
    __shared__ f16 Ts[64][72];
    const f16* sp = s + (size_t)(rt * 64) * C + ct * 64;
    #pragma unroll
    for (int e = 0; e < 2; ++e) {
        int idx = tid + e * 256;
        int row = idx >> 3, c8 = (idx & 7) * 8;
        *(float4*)&Ts[row][c8] = *(const float4*)(sp + (size_t)row * C + c8);
    }
    __syncthreads();
    f16* dp = d + (size_t)(ct * 64) * R + rt * 64;
    #pragma unroll
    for (int e = 0; e < 2; ++e) {
        int idx = tid + e * 256;
        int c = idx >> 3, r8 = (idx & 7) * 8;
        __align__(16) f16 tmp[8];
        #pragma unroll
        for (int j = 0; j < 8; ++j) tmp[j] = Ts[r8 + j][c];
        *(float4*)(dp + (size_t)c * R + r8) = *(float4*)tmp;
    }
}

__global__ __launch_bounds__(256) void k_tr16(const f16* __restrict__ src, f16* __restrict__ dst,
                                              int R, int C) {
    int b = blockIdx.x, tile = blockIdx.y, tid = threadIdx.x;
    int ctiles = C >> 6;
    int rt = tile / ctiles, ct = tile - rt * ctiles;
    tr16_body(src + (size_t)b * R * C, dst + (size_t)b * R * C, R, C, rt, ct, tid);
}

// dual-tensor transpose: z=0 -> (s0,d0), z=1 -> (s1,d1)
__global__ __launch_bounds__(256) void k_tr16p(const f16* __restrict__ s0, f16* __restrict__ d0,
                                               const f16* __restrict__ s1, f16* __restrict__ d1,
                                               int R, int C) {
    int b = blockIdx.x, tile = blockIdx.y, tid = threadIdx.x;
    int ctiles = C >> 6;
    int rt = tile / ctiles, ct = tile - rt * ctiles;
    const f16* s = (blockIdx.z == 0) ? s0 : s1;
    f16*       d = (blockIdx.z == 0) ? d0 : d1;
    tr16_body(s + (size_t)b * R * C, d + (size_t)b * R * C, R, C, rt, ct, tid);
}

// ---------------- K3: stage 1 MFMA: Fw[m][t][c] = w(t)*T[m][p]*f[p][c] ------
__global__ __launch_bounds__(256) void k_g1(const f16* __restrict__ xh, const f16* __restrict__ cF,
        const f16* __restrict__ sF, const double* __restrict__ w64,
        f16* __restrict__ FwR, f16* __restrict__ FwI) {
    __shared__ f16 Ac[64][40], An[64][40], Bs[64][40];
    int t = blockIdx.x, mt = blockIdx.y, tid = threadIdx.x;
    const f16* A0 = cF + (size_t)(mt * 64) * 512;
    const f16* A1 = sF + (size_t)(mt * 64) * 512;
    const f16* B  = xh + (size_t)t * (64 * 512);
    f32x4 acc[2][2][2];  // [tab][mf][nf]
    #pragma unroll
    for (int a = 0; a < 2; ++a)
        #pragma unroll
        for (int b = 0; b < 2; ++b)
            #pragma unroll
            for (int c = 0; c < 2; ++c) acc[a][b][c] = (f32x4){0.f, 0.f, 0.f, 0.f};
    int lane = tid & 63, wid = tid >> 6;
    int wm = wid & 1, wn = wid >> 1;
    int fr = lane & 15, g8 = (lane >> 4) * 8;
    int row = tid >> 2, k8 = (tid & 3) * 8;
    for (int kt = 0; kt < 16; ++kt) {
        float4 va = *(const float4*)(A0 + (size_t)row * 512 + kt * 32 + k8);
        float4 vn = *(const float4*)(A1 + (size_t)row * 512 + kt * 32 + k8);
        float4 vb = *(const float4*)(B  + (size_t)row * 512 + kt * 32 + k8);
        __syncthreads();
        *(float4*)&Ac[row][k8] = va;
        *(float4*)&An[row][k8] = vn;
        *(float4*)&Bs[row][k8] = vb;
        __syncthreads();
        f16x8 b0 = *(f16x8*)&Bs[wn * 32 + fr][g8];
        f16x8 b1 = *(f16x8*)&Bs[wn * 32 + 16 + fr][g8];
        f16x8 a0 = *(f16x8*)&Ac[wm * 32 + fr][g8];
        f16x8 a1 = *(f16x8*)&Ac[wm * 32 + 16 + fr][g8];
        f16x8 s0 = *(f16x8*)&An[wm * 32 + fr][g8];
        f16x8 s1 = *(f16x8*)&An[wm * 32 + 16 + fr][g8];
        acc[0][0][0] = __builtin_amdgcn_mfma_f32_16x16x32_f16(a0, b0, acc[0][0][0], 0, 0, 0);
        acc[0][0][1] = __builtin_amdgcn_mfma_f32_16x16x32_f16(a0, b1, acc[0][0][1], 0, 0, 0);
        acc[0][1][0] = __builtin_amdgcn_mfma_f32_16x16x32_f16(a1, b0, acc[0][1][0], 0, 0, 0);
        acc[0][1][1] = __builtin_amdgcn_mfma_f32_16x16x32_f16(a1, b1, acc[0][1][1], 0, 0, 0);
        acc[1][0][0] = __builtin_amdgcn_mfma_f32_16x16x32_f16(s0, b0, acc[1][0][0], 0, 0, 0);
        acc[1][0][1] = __builtin_amdgcn_mfma_f32_16x16x32_f16(s0, b1, acc[1][0][1], 0, 0, 0);
        acc[1][1][0] = __builtin_amdgcn_mfma_f32_16x16x32_f16(s1, b0, acc[1][1][0], 0, 0, 0);
        acc[1][1][1] = __builtin_amdgcn_mfma_f32_16x16x32_f16(s1, b1, acc[1][1][1], 0, 0, 0);
    }
    float wf = (float)w64[t];
    int rg = (lane >> 4) * 4;
    #pragma unroll
    for (int mf = 0; mf < 2; ++mf)
        #pragma unroll
        for (int nf = 0; nf < 2; ++nf) {
            int c = wn * 32 + nf * 16 + fr;
            #pragma unroll
            for (int r = 0; r < 4; ++r) {
                int m = mt * 64 + wm * 32 + mf * 16 + rg + r;
                FwR[((size_t)m * 256 + t) * 64 + c] = (f16)(acc[0][mf][nf][r] * wf);
                FwI[((size_t)m * 256 + t) * 64 + c] = (f16)(acc[1][mf][nf][r] * wf);
            }
        }
}

// ---------------- K4: stage 2 MFMA: Xh[m][l][c] = leg[l][t]*Fw[t][c] (f16 out)
__global__ __launch_bounds__(256) void k_g2(const f16* __restrict__ legh, const f16* __restrict__ BTr,
        const f16* __restrict__ BTi, f16* __restrict__ Xhr, f16* __restrict__ Xhi) {
    __shared__ f16 As[64][40], Br[64][40], Bi[64][40];
    int m = blockIdx.x, lt = blockIdx.y, tid = threadIdx.x;
    const f16* A  = legh + (size_t)m * (128 * 256) + (size_t)(lt * 64) * 256;
    const f16* B0 = BTr + (size_t)m * (64 * 256);
    const f16* B1 = BTi + (size_t)m * (64 * 256);
    f32x4 acc[2][2][2];  // [bsel][mf][nf]
    #pragma unroll
    for (int a = 0; a < 2; ++a)
        #pragma unroll
        for (int b = 0; b < 2; ++b)
            #pragma unroll
            for (int c = 0; c < 2; ++c) acc[a][b][c] = (f32x4){0.f, 0.f, 0.f, 0.f};
    int lane = tid & 63, wid = tid >> 6;
    int wm = wid & 1, wn = wid >> 1;
    int fr = lane & 15, g8 = (lane >> 4) * 8;
    int row = tid >> 2, k8 = (tid & 3) * 8;
    for (int kt = 0; kt < 8; ++kt) {
        float4 va = *(const float4*)(A  + (size_t)row * 256 + kt * 32 + k8);
        float4 vr = *(const float4*)(B0 + (size_t)row * 256 + kt * 32 + k8);
        float4 vi = *(const float4*)(B1 + (size_t)row * 256 + kt * 32 + k8);
        __syncthreads();
        *(float4*)&As[row][k8] = va;
        *(float4*)&Br[row][k8] = vr;
        *(float4*)&Bi[row][k8] = vi;
        __syncthreads();
        f16x8 a0 = *(f16x8*)&As[wm * 32 + fr][g8];
        f16x8 a1 = *(f16x8*)&As[wm * 32 + 16 + fr][g8];
        f16x8 r0 = *(f16x8*)&Br[wn * 32 + fr][g8];
        f16x8 r1 = *(f16x8*)&Br[wn * 32 + 16 + fr][g8];
        f16x8 i0 = *(f16x8*)&Bi[wn * 32 + fr][g8];
        f16x8 i1 = *(f16x8*)&Bi[wn * 32 + 16 + fr][g8];
        acc[0][0][0] = __builtin_amdgcn_mfma_f32_16x16x32_f16(a0, r0, acc[0][0][0], 0, 0, 0);
        acc[0][0][1] = __builtin_amdgcn_mfma_f32_16x16x32_f16(a0, r1, acc[0][0][1], 0, 0, 0);
        acc[0][1][0] = __builtin_amdgcn_mfma_f32_16x16x32_f16(a1, r0, acc[0][1][0], 0, 0, 0);
        acc[0][1][1] = __builtin_amdgcn_mfma_f32_16x16x32_f16(a1, r1, acc[0][1][1], 0, 0, 0);
        acc[1][0][0] = __builtin_amdgcn_mfma_f32_16x16x32_f16(a0, i0, acc[1][0][0], 0, 0, 0);
        acc[1][0][1] = __builtin_amdgcn_mfma_f32_16x16x32_f16(a0, i1, acc[1][0][1], 0, 0, 0);
        acc[1][1][0] = __builtin_amdgcn_mfma_f32_16x16x32_f16(a1, i0, acc[1][1][0], 0, 0, 0);
        acc[1][1][1] = __builtin_amdgcn_mfma_f32_16x16x32_f16(a1, i1, acc[1][1][1], 0, 0, 0);
    }
    int rg = (lane >> 4) * 4;
    #pragma unroll
    for (int mf = 0; mf < 2; ++mf)
        #pragma unroll
        for (int nf = 0; nf < 2; ++nf) {
            int c = wn * 32 + nf * 16 + fr;
            #pragma unroll
            for (int r = 0; r < 4; ++r) {
                int l = lt * 64 + wm * 32 + mf * 16 + rg + r;
                Xhr[(size_t)m * 8192 + l * 64 + c] = (f16)acc[0][mf][nf][r];
                Xhi[(size_t)m * 8192 + l * 64 + c] = (f16)acc[1][mf][nf][r];
            }
        }
}

// ---------------- K5: stage 3 MFMA: Out[m'][co] = Xe[m'][ci] . Rph[co][ci] --
__global__ __launch_bounds__(256) void k_s3m(const f16* __restrict__ Xhr, const f16* __restrict__ Xhi,
        const f16* __restrict__ Rphr, const f16* __restrict__ Rphi,
        f16* __restrict__ Or, f16* __restrict__ Oi) {
    __shared__ f16 Ars[64][72], Ais[64][72], Ans[64][72];
    int l = blockIdx.x, mt = blockIdx.y, tid = threadIdx.x;
    {
        int arow = tid >> 2;
        int mp = mt * 64 + arow;
        int mmv = mp - 127, am = mmv < 0 ? -mmv : mmv;
        unsigned short cj = (mmv < 0) ? 0x8000 : 0;
        u16x8 cjv = {cj, cj, cj, cj, cj, cj, cj, cj};
        u16x8 ngv = {0x8000, 0x8000, 0x8000, 0x8000, 0x8000, 0x8000, 0x8000, 0x8000};
        #pragma unroll
        for (int e = 0; e < 2; ++e) {
            int ci8 = (tid & 3) * 8 + e * 32;
            u16x8 vr = {0, 0, 0, 0, 0, 0, 0, 0};
            u16x8 vi = {0, 0, 0, 0, 0, 0, 0, 0};
            if (mp < 255) {
                vr = *(const u16x8*)(Xhr + (size_t)am * 8192 + l * 64 + ci8);
                vi = *(const u16x8*)(Xhi + (size_t)am * 8192 + l * 64 + ci8);
            }
            u16x8 vic = vi ^ cjv;       // conjugated imag
            u16x8 vin = vic ^ ngv;      // negated
            *(u16x8*)&Ars[arow][ci8] = vr;
            *(u16x8*)&Ais[arow][ci8] = vic;
            *(u16x8*)&Ans[arow][ci8] = vin;
        }
    }
    __syncthreads();
    int lane = tid & 63, wid = tid >> 6;
    int wm = wid & 1, wn = wid >> 1;
    int fr = lane & 15, g8 = (lane >> 4) * 8;
    const f16* Bre = Rphr + (size_t)l * 4096;
    const f16* Bim = Rphi + (size_t)l * 4096;
    f32x4 accr[2][2], acci[2][2];
    #pragma unroll
    for (int a = 0; a < 2; ++a)
        #pragma unroll
        for (int b = 0; b < 2; ++b) { accr[a][b] = (f32x4){0.f,0.f,0.f,0.f}; acci[a][b] = (f32x4){0.f,0.f,0.f,0.f}; }
    #pragma unroll
    for (int ks = 0; ks < 2; ++ks) {
        int ko = ks * 32 + g8;
        f16x8 ar0 = *(f16x8*)&Ars[wm * 32 + fr][ko];
        f16x8 ar1 = *(f16x8*)&Ars[wm * 32 + 16 + fr][ko];
        f16x8 ai0 = *(f16x8*)&Ais[wm * 32 + fr][ko];
        f16x8 ai1 = *(f16x8*)&Ais[wm * 32 + 16 + fr][ko];
        f16x8 an0 = *(f16x8*)&Ans[wm * 32 + fr][ko];
        f16x8 an1 = *(f16x8*)&Ans[wm * 32 + 16 + fr][ko];
        #pragma unroll
        for (int nf = 0; nf < 2; ++nf) {
            int brow = wn * 32 + nf * 16 + fr;
            f16x8 br = *(const f16x8*)(Bre + (size_t)brow * 64 + ko);
            f16x8 bi = *(const f16x8*)(Bim + (size_t)brow * 64 + ko);
            accr[0][nf] = __builtin_amdgcn_mfma_f32_16x16x32_f16(ar0, br, accr[0][nf], 0, 0, 0);
            accr[0][nf] = __builtin_amdgcn_mfma_f32_16x16x32_f16(an0, bi, accr[0][nf], 0, 0, 0);
            acci[0][nf] = __builtin_amdgcn_mfma_f32_16x16x32_f16(ar0, bi, acci[0][nf], 0, 0, 0);
            acci[0][nf] = __builtin_amdgcn_mfma_f32_16x16x32_f16(ai0, br, acci[0][nf], 0, 0, 0);
            accr[1][nf] = __builtin_amdgcn_mfma_f32_16x16x32_f16(ar1, br, accr[1][nf], 0, 0, 0);
            accr[1][nf] = __builtin_amdgcn_mfma_f32_16x16x32_f16(an1, bi, accr[1][nf], 0, 0, 0);
            acci[1][nf] = __builtin_amdgcn_mfma_f32_16x16x32_f16(ar1, bi, acci[1][nf], 0, 0, 0);
            acci[1][nf] = __builtin_amdgcn_mfma_f32_16x16x32_f16(ai1, br, acci[1][nf], 0, 0, 0);
        }
    }
    int rg = (lane >> 4) * 4;
    #pragma unroll
    for (int mf = 0; mf < 2; ++mf)
        #pragma unroll
        for (int nf = 0; nf < 2; ++nf) {
            int co = wn * 32 + nf * 16 + fr;
            #pragma unroll
            for (int r = 0; r < 4; ++r) {
                int mp = mt * 64 + wm * 32 + mf * 16 + rg + r;
                if (mp < 255) {
                    Or[(size_t)mp * 8192 + l * 64 + co] = (f16)accr[mf][nf][r];
                    Oi[(size_t)mp * 8192 + l * 64 + co] = (f16)acci[mf][nf][r];
                }
            }
        }
}

// ---------------- K6: stage 4 MFMA: G[2m'+u][t][c] = legT[t][l]*O_u[l][c] ---
__global__ __launch_bounds__(256) void k_g4(const f16* __restrict__ legT, const f16* __restrict__ OTr,
        const f16* __restrict__ OTi, f16* __restrict__ G) {
    __shared__ f16 As[64][40], Br[64][40], Bi[64][40];
    int mp = blockIdx.x, tt = blockIdx.y, tid = threadIdx.x;
    int mmv = mp - 127, am = mmv < 0 ? -mmv : mmv;
    const f16* A  = legT + (size_t)am * (256 * 128) + (size_t)(tt * 64) * 128;
    const f16* B0 = OTr + (size_t)mp * (64 * 128);
    const f16* B1 = OTi + (size_t)mp * (64 * 128);
    f32x4 acc[2][2][2];
    #pragma unroll
    for (int a = 0; a < 2; ++a)
        #pragma unroll
        for (int b = 0; b < 2; ++b)
            #pragma unroll
            for (int c = 0; c < 2; ++c) acc[a][b][c] = (f32x4){0.f, 0.f, 0.f, 0.f};
    int lane = tid & 63, wid = tid >> 6;
    int wm = wid & 1, wn = wid >> 1;
    int fr = lane & 15, g8 = (lane >> 4) * 8;
    int row = tid >> 2, k8 = (tid & 3) * 8;
    for (int kt = am >> 5; kt < 4; ++kt) {
        float4 va = *(const float4*)(A  + (size_t)row * 128 + kt * 32 + k8);
        float4 vr = *(const float4*)(B0 + (size_t)row * 128 + kt * 32 + k8);
        float4 vi = *(const float4*)(B1 + (size_t)row * 128 + kt * 32 + k8);
        __syncthreads();
        *(float4*)&As[row][k8] = va;
        *(float4*)&Br[row][k8] = vr;
        *(float4*)&Bi[row][k8] = vi;
        __syncthreads();
        f16x8 a0 = *(f16x8*)&As[wm * 32 + fr][g8];
        f16x8 a1 = *(f16x8*)&As[wm * 32 + 16 + fr][g8];
        f16x8 r0 = *(f16x8*)&Br[wn * 32 + fr][g8];
        f16x8 r1 = *(f16x8*)&Br[wn * 32 + 16 + fr][g8];
        f16x8 i0 = *(f16x8*)&Bi[wn * 32 + fr][g8];
        f16x8 i1 = *(f16x8*)&Bi[wn * 32 + 16 + fr][g8];
        acc[0][0][0] = __builtin_amdgcn_mfma_f32_16x16x32_f16(a0, r0, acc[0][0][0], 0, 0, 0);
        acc[0][0][1] = __builtin_amdgcn_mfma_f32_16x16x32_f16(a0, r1, acc[0][0][1], 0, 0, 0);
        acc[0][1][0] = __builtin_amdgcn_mfma_f32_16x16x32_f16(a1, r0, acc[0][1][0], 0, 0, 0);
        acc[0][1][1] = __builtin_amdgcn_mfma_f32_16x16x32_f16(a1, r1, acc[0][1][1], 0, 0, 0);
        acc[1][0][0] = __builtin_amdgcn_mfma_f32_16x16x32_f16(a0, i0, acc[1][0][0], 0, 0, 0);
        acc[1][0][1] = __builtin_amdgcn_mfma_f32_16x16x32_f16(a0, i1, acc[1][0][1], 0, 0, 0);
        acc[1][1][0] = __builtin_amdgcn_mfma_f32_16x16x32_f16(a1, i0, acc[1][1][0], 0, 0, 0);
        acc[1][1][1] = __builtin_amdgcn_mfma_f32_16x16x32_f16(a1, i1, acc[1][1][1], 0, 0, 0);
    }
    int rg = (lane >> 4) * 4;
    f16* gr = G + (size_t)(2 * mp) * (256 * 64);
    f16* gi = G + (size_t)(2 * mp + 1) * (256 * 64);
    #pragma unroll
    for (int mf = 0; mf < 2; ++mf)
        #pragma unroll
        for (int nf = 0; nf < 2; ++nf) {
            int c = wn * 32 + nf * 16 + fr;
            #pragma unroll
            for (int r = 0; r < 4; ++r) {
                int tl = tt * 64 + wm * 32 + mf * 16 + rg + r;
                gr[(size_t)tl * 64 + c] = (f16)acc[0][mf][nf][r];
                gi[(size_t)tl * 64 + c] = (f16)acc[1][mf][nf][r];
            }
        }
}

// ---------------- K7: stage 5 MFMA: out[t][p][c] = A5[p][k]*GT[t][c][k] -----
__global__ __launch_bounds__(256) void k_g5(const f16* __restrict__ A5, const f16* __restrict__ GT,
                                            float* __restrict__ out) {
    __shared__ f16 As[64][40], Bs[64][40];
    int t = blockIdx.x, pt = blockIdx.y, tid = threadIdx.x;
    const f16* A = A5 + (size_t)(pt * 64) * 512;
    const f16* B = GT + (size_t)t * (64 * 512);
    f32x4 acc[2][2];
    #pragma unroll
    for (int a = 0; a < 2; ++a)
        #pragma unroll
        for (int b = 0; b < 2; ++b) acc[a][b] = (f32x4){0.f, 0.f, 0.f, 0.f};
    int lane = tid & 63, wid = tid >> 6;
    int wm = wid & 1, wn = wid >> 1;
    int fr = lane & 15, g8 = (lane >> 4) * 8;
    int row = tid >> 2, k8 = (tid & 3) * 8;
    for (int kt = 0; kt < 16; ++kt) {
        float4 va = *(const float4*)(A + (size_t)row * 512 + kt * 32 + k8);
        float4 vb = *(const float4*)(B + (size_t)row * 512 + kt * 32 + k8);
        __syncthreads();
        *(float4*)&As[row][k8] = va;
        *(float4*)&Bs[row][k8] = vb;
        __syncthreads();
        f16x8 a0 = *(f16x8*)&As[wm * 32 + fr][g8];
        f16x8 a1 = *(f16x8*)&As[wm * 32 + 16 + fr][g8];
        f16x8 b0 = *(f16x8*)&Bs[wn * 32 + fr][g8];
        f16x8 b1 = *(f16x8*)&Bs[wn * 32 + 16 + fr][g8];
        acc[0][0] = __builtin_amdgcn_mfma_f32_16x16x32_f16(a0, b0, acc[0][0], 0, 0, 0);
        acc[0][1] = __builtin_amdgcn_mfma_f32_16x16x32_f16(a0, b1, acc[0][1], 0, 0, 0);
        acc[1][0] = __builtin_amdgcn_mfma_f32_16x16x32_f16(a1, b0, acc[1][0], 0, 0, 0);
        acc[1][1] = __builtin_amdgcn_mfma_f32_16x16x32_f16(a1, b1, acc[1][1], 0, 0, 0);
    }
    int rg = (lane >> 4) * 4;
    #pragma unroll
    for (int mf = 0; mf < 2; ++mf)
        #pragma unroll
        for (int nf = 0; nf < 2; ++nf) {
            int c = wn * 32 + nf * 16 + fr;
            #pragma unroll
            for (int r = 0; r < 4; ++r) {
                int p = pt * 64 + wm * 32 + mf * 16 + rg + r;
                if (p < NPHI) out[((size_t)t * NPHI + p) * 64 + c] = acc[mf][nf][r];
            }
        }
}

extern "C" void kernel_launch(void* const* d_in, const int* in_sizes, int n_in,
                              void* d_out, int out_size, void* d_ws, size_t ws_size,
                              hipStream_t stream) {
    const float* x    = (const float*)d_in[0];
    const float* temb = (const float*)d_in[1];
    const float* Ar   = (const float*)d_in[2];
    const float* Ai   = (const float*)d_in[3];
    const float* Rr   = (const float*)d_in[4];
    const float* Ri   = (const float*)d_in[5];
    float* out = (float*)d_out;

    char* ws = (char*)d_ws;
    size_t off = 0;
    auto alloc = [&](size_t bytes) -> void* {
        void* p = ws + off;
        off = (off + bytes + 255) & ~(size_t)255;
        return p;
    };
    double* x64  = (double*)alloc(256 * 8);
    double* w64  = (double*)alloc(256 * 8);
    float*  phi  = (float*)alloc(256 * 4);
    f16* legh  = (f16*)alloc((size_t)128 * 128 * 256 * 2);   // 8.39 MB
    f16* leghT = (f16*)alloc((size_t)128 * 256 * 128 * 2);   // 8.39 MB
    f16* cF    = (f16*)alloc((size_t)128 * 512 * 2);
    f16* sF    = (f16*)alloc((size_t)128 * 512 * 2);
    f16* A5    = (f16*)alloc((size_t)512 * 512 * 2);
    f16* R1    = (f16*)alloc((size_t)256 * 64 * 512 * 2);    // 16.78 MB: xh / GT
    f16* R2    = (f16*)alloc((size_t)512 * 256 * 64 * 2);    // 16.78 MB: Fw{R,I,RT,IT} / Gk
    f16* Xhr   = (f16*)alloc((size_t)128 * 128 * 64 * 2);    // 2.1 MB
    f16* Xhi   = (f16*)alloc((size_t)128 * 128 * 64 * 2);
    f16* Rphr  = (f16*)alloc((size_t)128 * 64 * 64 * 2);     // 1.05 MB
    f16* Rphi  = (f16*)alloc((size_t)128 * 64 * 64 * 2);
    f16* Or    = (f16*)alloc((size_t)255 * 128 * 64 * 2);
    f16* Oi    = (f16*)alloc((size_t)255 * 128 * 64 * 2);
    f16* OrT   = (f16*)alloc((size_t)255 * 64 * 128 * 2);
    f16* OiT   = (f16*)alloc((size_t)255 * 64 * 128 * 2);
    if (off > ws_size) return;

    f16* xh   = R1;
    f16* GT   = R1;
    f16* FwR  = R2;
    f16* FwI  = R2 + (size_t)2097152;
    f16* FwRT = R2 + (size_t)4194304;
    f16* FwIT = R2 + (size_t)6291456;
    f16* Gk   = R2;
    // NOTE: no memset of Gk pad rows (510,511) — A5 columns k>=510 are exactly 0,
    // and the stale pad data (tail of FwIT) is always finite, so k_g5's MFMA
    // contribution from those k is exactly 0. The 64KB hipMemsetAsync cost 40us.

    hipLaunchKernelGGL(k_gl_nodes, dim3(1),           dim3(256), 0, stream, x64, w64);
    hipLaunchKernelGGL(k_leg_h,    dim3(128),         dim3(256), 0, stream, x64, legh);
    hipLaunchKernelGGL(k_tr16,     dim3(128, 8),      dim3(256), 0, stream, legh, leghT, 128, 256);
    hipLaunchKernelGGL(k_tables_h, dim3(1024),        dim3(256), 0, stream, cF, sF, A5);
    hipLaunchKernelGGL(k_phi,      dim3(1),           dim3(128), 0, stream, Ar, Ai, temb, phi);
    hipLaunchKernelGGL(k_prep_R,   dim3(128),         dim3(256), 0, stream, Rr, Ri, phi, Rphr, Rphi);
    hipLaunchKernelGGL(k_convert,  dim3(256, 8),      dim3(256), 0, stream, x, xh);
    hipLaunchKernelGGL(k_g1,       dim3(256, 2),      dim3(256), 0, stream, xh, cF, sF, w64, FwR, FwI);
    hipLaunchKernelGGL(k_tr16p,    dim3(128, 4, 2),   dim3(256), 0, stream, FwR, FwRT, FwI, FwIT, 256, 64);
    hipLaunchKernelGGL(k_g2,       dim3(128, 2),      dim3(256), 0, stream, legh, FwRT, FwIT, Xhr, Xhi);
    hipLaunchKernelGGL(k_s3m,      dim3(128, 4),      dim3(256), 0, stream, Xhr, Xhi, Rphr, Rphi, Or, Oi);
    hipLaunchKernelGGL(k_tr16p,    dim3(255, 2, 2),   dim3(256), 0, stream, Or, OrT, Oi, OiT, 128, 64);
    hipLaunchKernelGGL(k_g4,       dim3(255, 4),      dim3(256), 0, stream, leghT, OrT, OiT, Gk);
    hipLaunchKernelGGL(k_tr16,     dim3(1, 2048),     dim3(256), 0, stream, Gk, GT, 512, 16384);
    hipLaunchKernelGGL(k_g5,       dim3(256, 8),      dim3(256), 0, stream, A5, GT, out);
}